// Round 3
// baseline (1015.929 us; speedup 1.0000x reference)
//
#include <hip/hip_runtime.h>
#include <stddef.h>

#define HH 96
#define WW 96
#define NPIX 9216
#define LBL 21
#define LPAD 32
#define RAD 9            // int(3 * POS_STD)
#define N_ITER 10
#define POS_W_C 3.0f
#define BI_W_C 10.0f
#define INV_XY (1.0f/80.0f)
#define INV_RGB (1.0f/13.0f)

typedef __bf16 bf16x8 __attribute__((ext_vector_type(8)));
typedef float  f32x4  __attribute__((ext_vector_type(4)));

// exp(-0.5*(d/3)^2), d = -9..9  (matches reference _gauss1d(3.0))
__device__ const float GK[2 * RAD + 1] = {
    0.01110900f, 0.02856548f, 0.06572886f, 0.13533528f, 0.24935220f,
    0.41111229f, 0.60653066f, 0.80073740f, 0.94595947f, 1.00000000f,
    0.94595947f, 0.80073740f, 0.60653066f, 0.41111229f, 0.24935220f,
    0.13533528f, 0.06572886f, 0.02856548f, 0.01110900f
};

__device__ __forceinline__ unsigned short f2bf(float f) {
    unsigned u = __float_as_uint(f);
    unsigned r = (u + 0x7fffu + ((u >> 16) & 1u)) >> 16;
    return (unsigned short)r;
}
__device__ __forceinline__ float bf2f(unsigned short s) {
    return __uint_as_float(((unsigned)s) << 16);
}

// ---------------------------------------------------------------- k_prep
__global__ void k_prep(const float* __restrict__ I,
                       float* __restrict__ fx, float* __restrict__ fy,
                       float* __restrict__ fr, float* __restrict__ fg,
                       float* __restrict__ fb, float* __restrict__ nsp) {
    int n = blockIdx.x * 256 + threadIdx.x;
    if (n >= NPIX) return;
    int y = n / WW, x = n % WW;
    fx[n] = (float)x * INV_XY;
    fy[n] = (float)y * INV_XY;
    fr[n] = I[n] * INV_RGB;
    fg[n] = I[NPIX + n] * INV_RGB;
    fb[n] = I[2 * NPIX + n] * INV_RGB;
    float sy = 0.f, sx = 0.f;
    #pragma unroll
    for (int d = -RAD; d <= RAD; ++d) {
        float g = GK[d + RAD];
        if ((unsigned)(y + d) < HH) sy += g;
        if ((unsigned)(x + d) < WW) sx += g;
    }
    nsp[n] = rsqrtf(sy * sx);
}

// ---------------------------------------------------------------- k_K
template <bool STORE>
__global__ void k_K(const float* __restrict__ fx, const float* __restrict__ fy,
                    const float* __restrict__ fr, const float* __restrict__ fg,
                    const float* __restrict__ fb,
                    float* __restrict__ nbi, unsigned short* __restrict__ K) {
    int i = blockIdx.x;
    int t = threadIdx.x;
    float xi = fx[i], yi = fy[i], ri = fr[i], gi = fg[i], bi = fb[i];
    float sum = 0.f;
    for (int jt = t; jt < NPIX / 4; jt += 256) {
        int j = jt * 4;
        float4 vx = *(const float4*)(fx + j);
        float4 vy = *(const float4*)(fy + j);
        float4 vr = *(const float4*)(fr + j);
        float4 vg = *(const float4*)(fg + j);
        float4 vb = *(const float4*)(fb + j);
        float k0, k1, k2, k3;
        {
            float dx = xi - vx.x, dy = yi - vy.x, dr = ri - vr.x, dg = gi - vg.x, db = bi - vb.x;
            k0 = __expf(-0.5f * (dx*dx + dy*dy + dr*dr + dg*dg + db*db));
        }
        {
            float dx = xi - vx.y, dy = yi - vy.y, dr = ri - vr.y, dg = gi - vg.y, db = bi - vb.y;
            k1 = __expf(-0.5f * (dx*dx + dy*dy + dr*dr + dg*dg + db*db));
        }
        {
            float dx = xi - vx.z, dy = yi - vy.z, dr = ri - vr.z, dg = gi - vg.z, db = bi - vb.z;
            k2 = __expf(-0.5f * (dx*dx + dy*dy + dr*dr + dg*dg + db*db));
        }
        {
            float dx = xi - vx.w, dy = yi - vy.w, dr = ri - vr.w, dg = gi - vg.w, db = bi - vb.w;
            k3 = __expf(-0.5f * (dx*dx + dy*dy + dr*dr + dg*dg + db*db));
        }
        sum += (k0 + k1) + (k2 + k3);
        if (STORE) {
            ushort4 s;
            s.x = f2bf(k0); s.y = f2bf(k1); s.z = f2bf(k2); s.w = f2bf(k3);
            *(ushort4*)(K + (size_t)i * NPIX + j) = s;
        }
    }
    __shared__ float red[256];
    red[t] = sum;
    __syncthreads();
    #pragma unroll
    for (int s = 128; s > 0; s >>= 1) {
        if (t < s) red[t] += red[t + s];
        __syncthreads();
    }
    if (t == 0) nbi[i] = rsqrtf(red[0]);
}

// ---------------------------------------------------------------- k_q0
__global__ void k_q0(const float* __restrict__ U, const float* __restrict__ nbi,
                     const float* __restrict__ nsp, float* __restrict__ A,
                     unsigned short* __restrict__ Qt0, unsigned short* __restrict__ Qt1) {
    int n = blockIdx.x * 256 + threadIdx.x;
    if (n >= NPIX) return;
    float v[LBL];
    float mx = -1e30f;
    #pragma unroll
    for (int l = 0; l < LBL; ++l) { v[l] = -U[l * NPIX + n]; mx = fmaxf(mx, v[l]); }
    float s = 0.f;
    #pragma unroll
    for (int l = 0; l < LBL; ++l) { v[l] = __expf(v[l] - mx); s += v[l]; }
    float inv = 1.f / s;
    float nb = nbi[n];
    float ns = nsp[n];
    #pragma unroll
    for (int l = 0; l < LBL; ++l) {
        float q = v[l] * inv;
        A[l * NPIX + n] = ns * q;
        Qt0[l * NPIX + n] = f2bf(nb * q);
    }
    #pragma unroll
    for (int l = LBL; l < LPAD; ++l) { Qt0[l * NPIX + n] = 0; Qt1[l * NPIX + n] = 0; }
}

// ---------------------------------------------------------------- k_sp
// fused separable conv: one block per (label, 16-row band); vertical from
// global (L2-hot), horizontal from LDS. SP = POS_W * nsp * Gx(Gy(A))
__global__ void k_sp(const float* __restrict__ A, const float* __restrict__ nsp,
                     float* __restrict__ SP) {
    __shared__ float ty[16][WW];
    int l = blockIdx.x / 6;
    int y0 = (blockIdx.x % 6) * 16;
    int t = threadIdx.x;
    const float* Al = A + (size_t)l * NPIX;
    #pragma unroll
    for (int c = 0; c < 6; ++c) {
        int p = t + c * 256;          // 0..1535
        int yy = p / WW, x = p % WW;
        int y = y0 + yy;
        float s = 0.f;
        #pragma unroll
        for (int d = -RAD; d <= RAD; ++d) {
            int yd = y + d;
            if ((unsigned)yd < HH) s += GK[d + RAD] * Al[yd * WW + x];
        }
        ty[yy][x] = s;
    }
    __syncthreads();
    #pragma unroll
    for (int c = 0; c < 6; ++c) {
        int p = t + c * 256;
        int yy = p / WW, x = p % WW;
        float s = 0.f;
        #pragma unroll
        for (int d = -RAD; d <= RAD; ++d) {
            int xd = x + d;
            if ((unsigned)xd < WW) s += GK[d + RAD] * ty[yy][xd];
        }
        int pp = (y0 + yy) * WW + x;
        SP[(size_t)l * NPIX + pp] = POS_W_C * nsp[pp] * s;
    }
}

// ---------------------------------------------------------------- k_bi_fast
// 288 blocks x 4 waves. Each block: 32 output pixels (two 16-row i-tiles),
// each wave covers a j-quarter. 2-bank register pipeline keeps 12 16B loads
// in flight per lane. LDS cross-wave reduce; waves 0/1 do fused softmax
// epilogue for tile 0/1.
__global__ void __launch_bounds__(256)
k_bi_fast(const unsigned short* __restrict__ K, const unsigned short* __restrict__ Qt,
          const float* __restrict__ U, const float* __restrict__ SP,
          const float* __restrict__ nbi, const float* __restrict__ nsp,
          float* __restrict__ Qo, float* __restrict__ Ao,
          unsigned short* __restrict__ Qto) {
    int tid = threadIdx.x;
    int lane = tid & 63;
    int wv = tid >> 6;      // 0..3, j-split
    int m  = lane & 15;     // A row / B col(label) index
    int kh = lane >> 4;     // k-quad
    int i0 = blockIdx.x * 32;

    const int JW = NPIX / 4;           // 2304 j per wave
    const int ITERS = JW / 32;         // 72 jt steps
    const int G = 3;                   // jt groups per bank
    const int CHUNKS = ITERS / G;      // 24
    int jbase = wv * JW;

    const bf16x8* pa0 = (const bf16x8*)(K  + (size_t)(i0 + m)      * NPIX + jbase + kh * 8);
    const bf16x8* pa1 = (const bf16x8*)(K  + (size_t)(i0 + 16 + m) * NPIX + jbase + kh * 8);
    const bf16x8* pb0 = (const bf16x8*)(Qt + (size_t)m             * NPIX + jbase + kh * 8);
    const bf16x8* pb1 = (const bf16x8*)(Qt + (size_t)(m + 16)      * NPIX + jbase + kh * 8);

    f32x4 acc00 = {0.f,0.f,0.f,0.f}, acc01 = {0.f,0.f,0.f,0.f};
    f32x4 acc10 = {0.f,0.f,0.f,0.f}, acc11 = {0.f,0.f,0.f,0.f};

    bf16x8 bA0[2][G], bA1[2][G], bB0[2][G], bB1[2][G];

#define LOADB(B, C) do { \
    _Pragma("unroll") \
    for (int p = 0; p < G; ++p) { \
        int jt4 = ((C) * G + p) * 4; \
        bA0[B][p] = pa0[jt4]; \
        bA1[B][p] = pa1[jt4]; \
        bB0[B][p] = pb0[jt4]; \
        bB1[B][p] = pb1[jt4]; \
    } } while (0)

#define COMPB(B) do { \
    _Pragma("unroll") \
    for (int p = 0; p < G; ++p) { \
        acc00 = __builtin_amdgcn_mfma_f32_16x16x32_bf16(bA0[B][p], bB0[B][p], acc00, 0, 0, 0); \
        acc01 = __builtin_amdgcn_mfma_f32_16x16x32_bf16(bA0[B][p], bB1[B][p], acc01, 0, 0, 0); \
        acc10 = __builtin_amdgcn_mfma_f32_16x16x32_bf16(bA1[B][p], bB0[B][p], acc10, 0, 0, 0); \
        acc11 = __builtin_amdgcn_mfma_f32_16x16x32_bf16(bA1[B][p], bB1[B][p], acc11, 0, 0, 0); \
    } } while (0)

    LOADB(0, 0);
    for (int c = 0; c < CHUNKS; c += 2) {
        LOADB(1, c + 1);
        COMPB(0);
        if (c + 2 < CHUNKS) LOADB(0, c + 2);
        COMPB(1);
    }
#undef LOADB
#undef COMPB

    // cross-wave j reduction: red[wv][reg][lane], reg = tile*8 + half*4 + r
    __shared__ float red[4][16][64];
    #pragma unroll
    for (int r = 0; r < 4; ++r) {
        red[wv][r][lane]      = acc00[r];
        red[wv][4 + r][lane]  = acc01[r];
        red[wv][8 + r][lane]  = acc10[r];
        red[wv][12 + r][lane] = acc11[r];
    }
    __syncthreads();
    if (wv >= 2) return;

    int tb = wv * 8;   // wave0 -> tile0 regs 0..7, wave1 -> tile1 regs 8..15
    float a0[4], a1[4];
    #pragma unroll
    for (int r = 0; r < 4; ++r) {
        a0[r] = red[0][tb + r][lane]     + red[1][tb + r][lane]
              + red[2][tb + r][lane]     + red[3][tb + r][lane];
        a1[r] = red[0][tb + 4 + r][lane] + red[1][tb + 4 + r][lane]
              + red[2][tb + 4 + r][lane] + red[3][tb + 4 + r][lane];
    }

    // epilogue: C/D layout col(label)=lane&15, row=kh*4+reg
    int n0 = m;
    int l1 = m + 16;
    int ibase = i0 + wv * 16;
    #pragma unroll
    for (int r = 0; r < 4; ++r) {
        int i = ibase + kh * 4 + r;
        float nb = nbi[i];
        float lg0 = -U[n0 * NPIX + i] + SP[n0 * NPIX + i] + BI_W_C * nb * a0[r];
        float lg1 = (l1 < LBL)
                  ? (-U[l1 * NPIX + i] + SP[l1 * NPIX + i] + BI_W_C * nb * a1[r])
                  : -1e30f;
        float mx = fmaxf(lg0, lg1);
        #pragma unroll
        for (int off = 1; off < 16; off <<= 1) mx = fmaxf(mx, __shfl_xor(mx, off, 16));
        float e0 = __expf(lg0 - mx);
        float e1 = (l1 < LBL) ? __expf(lg1 - mx) : 0.f;
        float s = e0 + e1;
        #pragma unroll
        for (int off = 1; off < 16; off <<= 1) s += __shfl_xor(s, off, 16);
        float inv = 1.f / s;
        float ns = nsp[i];
        float q0 = e0 * inv;
        Qo[n0 * NPIX + i] = q0;
        Ao[n0 * NPIX + i] = ns * q0;
        Qto[n0 * NPIX + i] = f2bf(nb * q0);
        if (l1 < LBL) {
            float q1 = e1 * inv;
            Qo[l1 * NPIX + i] = q1;
            Ao[l1 * NPIX + i] = ns * q1;
            Qto[l1 * NPIX + i] = f2bf(nb * q1);
        }
    }
}

// ---------------------------------------------------------------- k_bi_slow
// fallback when ws too small for K (unused when workspace fits K)
__global__ void k_bi_slow(const float* __restrict__ fx, const float* __restrict__ fy,
                          const float* __restrict__ fr, const float* __restrict__ fg,
                          const float* __restrict__ fb,
                          const float* __restrict__ nbi, const unsigned short* __restrict__ Qt,
                          const float* __restrict__ U, const float* __restrict__ SP,
                          const float* __restrict__ nsp,
                          float* __restrict__ Qo, float* __restrict__ Ao,
                          unsigned short* __restrict__ Qto) {
    int t = threadIdx.x;
    int px = t & 15, st = t >> 4;
    int i = blockIdx.x * 16 + px;
    float xi = fx[i], yi = fy[i], ri = fr[i], gi = fg[i], bi = fb[i];
    float acc[LBL];
    #pragma unroll
    for (int l = 0; l < LBL; ++l) acc[l] = 0.f;
    int j0 = st * (NPIX / 16);
    for (int j = j0; j < j0 + NPIX / 16; ++j) {
        float dx = xi - fx[j], dy = yi - fy[j];
        float dr = ri - fr[j], dg = gi - fg[j], db = bi - fb[j];
        float D = dx*dx + dy*dy + dr*dr + dg*dg + db*db;
        float w = __expf(-0.5f * D);
        #pragma unroll
        for (int l = 0; l < LBL; ++l) acc[l] += w * bf2f(Qt[l * NPIX + j]);
    }
    __shared__ float red[16][LBL];
    if (st == 0) {
        #pragma unroll
        for (int l = 0; l < LBL; ++l) red[px][l] = acc[l];
    }
    __syncthreads();
    for (int s = 1; s < 16; ++s) {
        if (st == s) {
            #pragma unroll
            for (int l = 0; l < LBL; ++l) red[px][l] += acc[l];
        }
        __syncthreads();
    }
    if (t < 16) {
        int i2 = blockIdx.x * 16 + t;
        float nb = nbi[i2];
        float ns = nsp[i2];
        float v[LBL];
        float mx = -1e30f;
        #pragma unroll
        for (int l = 0; l < LBL; ++l) {
            v[l] = -U[l * NPIX + i2] + SP[l * NPIX + i2] + BI_W_C * nb * red[t][l];
            mx = fmaxf(mx, v[l]);
        }
        float s = 0.f;
        #pragma unroll
        for (int l = 0; l < LBL; ++l) { v[l] = __expf(v[l] - mx); s += v[l]; }
        float inv = 1.f / s;
        #pragma unroll
        for (int l = 0; l < LBL; ++l) {
            float q = v[l] * inv;
            Qo[l * NPIX + i2] = q;
            Ao[l * NPIX + i2] = ns * q;
            Qto[l * NPIX + i2] = f2bf(nb * q);
        }
    }
}

// ---------------------------------------------------------------- launch
extern "C" void kernel_launch(void* const* d_in, const int* in_sizes, int n_in,
                              void* d_out, int out_size, void* d_ws, size_t ws_size,
                              hipStream_t stream) {
    const float* U = (const float*)d_in[0];
    const float* I = (const float*)d_in[1];

    char* w = (char*)d_ws;
    float* fx  = (float*)w;                 w += NPIX * sizeof(float);
    float* fy  = (float*)w;                 w += NPIX * sizeof(float);
    float* fr  = (float*)w;                 w += NPIX * sizeof(float);
    float* fg  = (float*)w;                 w += NPIX * sizeof(float);
    float* fb  = (float*)w;                 w += NPIX * sizeof(float);
    float* nsp = (float*)w;                 w += NPIX * sizeof(float);
    float* nbi = (float*)w;                 w += NPIX * sizeof(float);
    float* A   = (float*)w;                 w += (size_t)LBL * NPIX * sizeof(float);
    float* SP  = (float*)w;                 w += (size_t)LBL * NPIX * sizeof(float);
    unsigned short* Qtb[2];
    Qtb[0] = (unsigned short*)w;            w += (size_t)LPAD * NPIX * sizeof(unsigned short);
    Qtb[1] = (unsigned short*)w;            w += (size_t)LPAD * NPIX * sizeof(unsigned short);
    unsigned short* K = (unsigned short*)w;
    size_t need = (size_t)(w - (char*)d_ws) + (size_t)NPIX * NPIX * sizeof(unsigned short);
    bool fast = (ws_size >= need);

    float* Qout = (float*)d_out;   // overwritten every iteration; final iter is the answer

    k_prep<<<(NPIX + 255) / 256, 256, 0, stream>>>(I, fx, fy, fr, fg, fb, nsp);
    if (fast) k_K<true ><<<NPIX, 256, 0, stream>>>(fx, fy, fr, fg, fb, nbi, K);
    else      k_K<false><<<NPIX, 256, 0, stream>>>(fx, fy, fr, fg, fb, nbi, nullptr);
    k_q0<<<(NPIX + 255) / 256, 256, 0, stream>>>(U, nbi, nsp, A, Qtb[0], Qtb[1]);

    for (int t = 0; t < N_ITER; ++t) {
        const unsigned short* Qtin = Qtb[t & 1];
        unsigned short* Qtout = Qtb[(t + 1) & 1];
        k_sp<<<LBL * 6, 256, 0, stream>>>(A, nsp, SP);
        if (fast)
            k_bi_fast<<<NPIX / 32, 256, 0, stream>>>(K, Qtin, U, SP, nbi, nsp, Qout, A, Qtout);
        else
            k_bi_slow<<<NPIX / 16, 256, 0, stream>>>(fx, fy, fr, fg, fb, nbi, Qtin, U, SP, nsp, Qout, A, Qtout);
    }
}

// Round 4
// 792.881 us; speedup vs baseline: 1.2813x; 1.2813x over previous
//
#include <hip/hip_runtime.h>
#include <stddef.h>

#define HH 96
#define WW 96
#define NPIX 9216
#define LBL 21
#define LPAD 32
#define RAD 9            // int(3 * POS_STD)
#define N_ITER 10
#define POS_W_C 3.0f
#define BI_W_C 10.0f
#define INV_XY (1.0f/80.0f)
#define INV_RGB (1.0f/13.0f)

// bilateral GEMM blocking
#define JCH 12                       // j chunks (blocks) per i-tile
#define JC (NPIX / JCH)              // 768 columns per chunk
#define ROWB (JC * 2 + 16)           // LDS row stride bytes (+16 pad: 388 words % 32 = 4 -> benign)
#define CHROW (ROWB / 16)            // 97 16B-chunks per LDS row
#define TOTCH (32 * CHROW)           // 3104 chunks to stage
#define ITILE 64                     // rows per block (4 waves x 16)
#define NIT (NPIX / ITILE)           // 144 i-tiles

typedef __bf16 bf16x8 __attribute__((ext_vector_type(8)));
typedef float  f32x4  __attribute__((ext_vector_type(4)));

// exp(-0.5*(d/3)^2), d = -9..9  (matches reference _gauss1d(3.0))
__device__ const float GK[2 * RAD + 1] = {
    0.01110900f, 0.02856548f, 0.06572886f, 0.13533528f, 0.24935220f,
    0.41111229f, 0.60653066f, 0.80073740f, 0.94595947f, 1.00000000f,
    0.94595947f, 0.80073740f, 0.60653066f, 0.41111229f, 0.24935220f,
    0.13533528f, 0.06572886f, 0.02856548f, 0.01110900f
};

__device__ __forceinline__ unsigned short f2bf(float f) {
    unsigned u = __float_as_uint(f);
    unsigned r = (u + 0x7fffu + ((u >> 16) & 1u)) >> 16;
    return (unsigned short)r;
}
__device__ __forceinline__ float bf2f(unsigned short s) {
    return __uint_as_float(((unsigned)s) << 16);
}

// ---------------------------------------------------------------- k_prep
__global__ void k_prep(const float* __restrict__ I,
                       float* __restrict__ fx, float* __restrict__ fy,
                       float* __restrict__ fr, float* __restrict__ fg,
                       float* __restrict__ fb, float* __restrict__ nsp) {
    int n = blockIdx.x * 256 + threadIdx.x;
    if (n >= NPIX) return;
    int y = n / WW, x = n % WW;
    fx[n] = (float)x * INV_XY;
    fy[n] = (float)y * INV_XY;
    fr[n] = I[n] * INV_RGB;
    fg[n] = I[NPIX + n] * INV_RGB;
    fb[n] = I[2 * NPIX + n] * INV_RGB;
    float sy = 0.f, sx = 0.f;
    #pragma unroll
    for (int d = -RAD; d <= RAD; ++d) {
        float g = GK[d + RAD];
        if ((unsigned)(y + d) < HH) sy += g;
        if ((unsigned)(x + d) < WW) sx += g;
    }
    nsp[n] = rsqrtf(sy * sx);
}

// ---------------------------------------------------------------- k_K
template <bool STORE>
__global__ void k_K(const float* __restrict__ fx, const float* __restrict__ fy,
                    const float* __restrict__ fr, const float* __restrict__ fg,
                    const float* __restrict__ fb,
                    float* __restrict__ nbi, unsigned short* __restrict__ K) {
    int i = blockIdx.x;
    int t = threadIdx.x;
    float xi = fx[i], yi = fy[i], ri = fr[i], gi = fg[i], bi = fb[i];
    float sum = 0.f;
    for (int jt = t; jt < NPIX / 4; jt += 256) {
        int j = jt * 4;
        float4 vx = *(const float4*)(fx + j);
        float4 vy = *(const float4*)(fy + j);
        float4 vr = *(const float4*)(fr + j);
        float4 vg = *(const float4*)(fg + j);
        float4 vb = *(const float4*)(fb + j);
        float k0, k1, k2, k3;
        {
            float dx = xi - vx.x, dy = yi - vy.x, dr = ri - vr.x, dg = gi - vg.x, db = bi - vb.x;
            k0 = __expf(-0.5f * (dx*dx + dy*dy + dr*dr + dg*dg + db*db));
        }
        {
            float dx = xi - vx.y, dy = yi - vy.y, dr = ri - vr.y, dg = gi - vg.y, db = bi - vb.y;
            k1 = __expf(-0.5f * (dx*dx + dy*dy + dr*dr + dg*dg + db*db));
        }
        {
            float dx = xi - vx.z, dy = yi - vy.z, dr = ri - vr.z, dg = gi - vg.z, db = bi - vb.z;
            k2 = __expf(-0.5f * (dx*dx + dy*dy + dr*dr + dg*dg + db*db));
        }
        {
            float dx = xi - vx.w, dy = yi - vy.w, dr = ri - vr.w, dg = gi - vg.w, db = bi - vb.w;
            k3 = __expf(-0.5f * (dx*dx + dy*dy + dr*dr + dg*dg + db*db));
        }
        sum += (k0 + k1) + (k2 + k3);
        if (STORE) {
            ushort4 s;
            s.x = f2bf(k0); s.y = f2bf(k1); s.z = f2bf(k2); s.w = f2bf(k3);
            *(ushort4*)(K + (size_t)i * NPIX + j) = s;
        }
    }
    __shared__ float red[256];
    red[t] = sum;
    __syncthreads();
    #pragma unroll
    for (int s = 128; s > 0; s >>= 1) {
        if (t < s) red[t] += red[t + s];
        __syncthreads();
    }
    if (t == 0) nbi[i] = rsqrtf(red[0]);
}

// ---------------------------------------------------------------- k_q0
__global__ void k_q0(const float* __restrict__ U, const float* __restrict__ nbi,
                     const float* __restrict__ nsp, float* __restrict__ A,
                     unsigned short* __restrict__ Qt0, unsigned short* __restrict__ Qt1) {
    int n = blockIdx.x * 256 + threadIdx.x;
    if (n >= NPIX) return;
    float v[LBL];
    float mx = -1e30f;
    #pragma unroll
    for (int l = 0; l < LBL; ++l) { v[l] = -U[l * NPIX + n]; mx = fmaxf(mx, v[l]); }
    float s = 0.f;
    #pragma unroll
    for (int l = 0; l < LBL; ++l) { v[l] = __expf(v[l] - mx); s += v[l]; }
    float inv = 1.f / s;
    float nb = nbi[n];
    float ns = nsp[n];
    #pragma unroll
    for (int l = 0; l < LBL; ++l) {
        float q = v[l] * inv;
        A[l * NPIX + n] = ns * q;
        Qt0[l * NPIX + n] = f2bf(nb * q);
    }
    #pragma unroll
    for (int l = LBL; l < LPAD; ++l) { Qt0[l * NPIX + n] = 0; Qt1[l * NPIX + n] = 0; }
}

// ---------------------------------------------------------------- k_sp
// fused separable conv, one block per (label, 8-row band): 252 blocks ~ 1/CU
__global__ void k_sp(const float* __restrict__ A, const float* __restrict__ nsp,
                     float* __restrict__ SP) {
    __shared__ float ty[8][WW];
    int l = blockIdx.x / 12;
    int y0 = (blockIdx.x % 12) * 8;
    int t = threadIdx.x;
    const float* Al = A + (size_t)l * NPIX;
    #pragma unroll
    for (int c = 0; c < 3; ++c) {
        int p = t + c * 256;          // 0..767
        int yy = p / WW, x = p % WW;
        int y = y0 + yy;
        float s = 0.f;
        #pragma unroll
        for (int d = -RAD; d <= RAD; ++d) {
            int yd = y + d;
            if ((unsigned)yd < HH) s += GK[d + RAD] * Al[yd * WW + x];
        }
        ty[yy][x] = s;
    }
    __syncthreads();
    #pragma unroll
    for (int c = 0; c < 3; ++c) {
        int p = t + c * 256;
        int yy = p / WW, x = p % WW;
        float s = 0.f;
        #pragma unroll
        for (int d = -RAD; d <= RAD; ++d) {
            int xd = x + d;
            if ((unsigned)xd < WW) s += GK[d + RAD] * ty[yy][xd];
        }
        int pp = (y0 + yy) * WW + x;
        SP[(size_t)l * NPIX + pp] = POS_W_C * nsp[pp] * s;
    }
}

// ---------------------------------------------------------------- k_bi_fast
// grid = NIT i-tiles x JCH j-chunks. Block: stage Qt[32][768] chunk into LDS,
// 4 waves each own 16 i-rows, stream K from global, MFMA against LDS B-frags.
// Partial sums (per j-chunk) written to P; k_red reduces + softmax.
__global__ void __launch_bounds__(256)
k_bi_fast(const unsigned short* __restrict__ K, const unsigned short* __restrict__ Qt,
          float* __restrict__ P) {
    __shared__ __align__(16) unsigned short Bsh[32 * ROWB / 2];  // 49,664 B
    int tid = threadIdx.x;
    int bid = blockIdx.x;
    int jc = bid / NIT;            // 0..11
    int it = bid % NIT;            // 0..143
    int base_j = jc * JC;

    // ---- stage Qt chunk: 3104 16B chunks, rows padded to 1552 B
    for (int itn = 0; itn < (TOTCH + 255) / 256; ++itn) {
        int c = itn * 256 + tid;
        if (c < TOTCH) {
            int l = c / CHROW;
            int off = c - l * CHROW;                 // 0..96
            int off16 = (off == CHROW - 1) ? 0 : off; // pad chunk: load row start (never read)
            uint4 v = *(const uint4*)(Qt + (size_t)l * NPIX + base_j + off16 * 8);
            *((uint4*)Bsh + c) = v;
        }
    }
    __syncthreads();

    int lane = tid & 63;
    int wv = tid >> 6;      // 0..3 -> i-subtile
    int m  = lane & 15;
    int kh = lane >> 4;

    int i0 = it * ITILE + wv * 16;
    const bf16x8* pa = (const bf16x8*)(K + (size_t)(i0 + m) * NPIX + base_j + kh * 8);
    const char* lb0 = (const char*)Bsh + m * ROWB + kh * 16;
    const char* lb1 = (const char*)Bsh + (m + 16) * ROWB + kh * 16;

    f32x4 acc0 = {0.f, 0.f, 0.f, 0.f};
    f32x4 acc1 = {0.f, 0.f, 0.f, 0.f};

    #pragma unroll 8
    for (int jt = 0; jt < JC / 32; ++jt) {     // 24 iters
        bf16x8 av = pa[jt * 4];
        bf16x8 b0 = *(const bf16x8*)(lb0 + jt * 64);
        bf16x8 b1 = *(const bf16x8*)(lb1 + jt * 64);
        acc0 = __builtin_amdgcn_mfma_f32_16x16x32_bf16(av, b0, acc0, 0, 0, 0);
        acc1 = __builtin_amdgcn_mfma_f32_16x16x32_bf16(av, b1, acc1, 0, 0, 0);
    }

    // partials: P[jc][i][32] fp32; C/D layout col(label)=m, row=kh*4+r
    float* Pp = P + ((size_t)jc * NPIX) * 32;
    #pragma unroll
    for (int r = 0; r < 4; ++r) {
        int i = i0 + kh * 4 + r;
        Pp[(size_t)i * 32 + m]      = acc0[r];
        Pp[(size_t)i * 32 + m + 16] = acc1[r];
    }
}

// ---------------------------------------------------------------- k_red
// reduce 12 j-chunk partials, fused softmax epilogue, emit Q/A/Qt
__global__ void k_red(const float* __restrict__ P, const float* __restrict__ U,
                      const float* __restrict__ SP, const float* __restrict__ nbi,
                      const float* __restrict__ nsp,
                      float* __restrict__ Qo, float* __restrict__ Ao,
                      unsigned short* __restrict__ Qto) {
    int i = blockIdx.x * 256 + threadIdx.x;
    if (i >= NPIX) return;
    float4 s[6] = {{0,0,0,0},{0,0,0,0},{0,0,0,0},{0,0,0,0},{0,0,0,0},{0,0,0,0}};
    #pragma unroll
    for (int jc = 0; jc < JCH; ++jc) {
        const float4* p = (const float4*)(P + ((size_t)jc * NPIX + i) * 32);
        #pragma unroll
        for (int q = 0; q < 6; ++q) s[q] += p[q];
    }
    float bi[24];
    #pragma unroll
    for (int q = 0; q < 6; ++q) *(float4*)(bi + 4 * q) = s[q];

    float nb = nbi[i];
    float ns = nsp[i];
    float v[LBL];
    float mx = -1e30f;
    #pragma unroll
    for (int l = 0; l < LBL; ++l) {
        v[l] = -U[l * NPIX + i] + SP[l * NPIX + i] + BI_W_C * nb * bi[l];
        mx = fmaxf(mx, v[l]);
    }
    float ssum = 0.f;
    #pragma unroll
    for (int l = 0; l < LBL; ++l) { v[l] = __expf(v[l] - mx); ssum += v[l]; }
    float inv = 1.f / ssum;
    #pragma unroll
    for (int l = 0; l < LBL; ++l) {
        float q = v[l] * inv;
        Qo[l * NPIX + i] = q;
        Ao[l * NPIX + i] = ns * q;
        Qto[l * NPIX + i] = f2bf(nb * q);
    }
}

// ---------------------------------------------------------------- k_bi_slow
// fallback when ws too small for K (correct but slow)
__global__ void k_bi_slow(const float* __restrict__ fx, const float* __restrict__ fy,
                          const float* __restrict__ fr, const float* __restrict__ fg,
                          const float* __restrict__ fb,
                          const float* __restrict__ nbi, const unsigned short* __restrict__ Qt,
                          const float* __restrict__ U, const float* __restrict__ SP,
                          const float* __restrict__ nsp,
                          float* __restrict__ Qo, float* __restrict__ Ao,
                          unsigned short* __restrict__ Qto) {
    int t = threadIdx.x;
    int px = t & 15, st = t >> 4;
    int i = blockIdx.x * 16 + px;
    float xi = fx[i], yi = fy[i], ri = fr[i], gi = fg[i], bi = fb[i];
    float acc[LBL];
    #pragma unroll
    for (int l = 0; l < LBL; ++l) acc[l] = 0.f;
    int j0 = st * (NPIX / 16);
    for (int j = j0; j < j0 + NPIX / 16; ++j) {
        float dx = xi - fx[j], dy = yi - fy[j];
        float dr = ri - fr[j], dg = gi - fg[j], db = bi - fb[j];
        float D = dx*dx + dy*dy + dr*dr + dg*dg + db*db;
        float w = __expf(-0.5f * D);
        #pragma unroll
        for (int l = 0; l < LBL; ++l) acc[l] += w * bf2f(Qt[l * NPIX + j]);
    }
    __shared__ float red[16][LBL];
    if (st == 0) {
        #pragma unroll
        for (int l = 0; l < LBL; ++l) red[px][l] = acc[l];
    }
    __syncthreads();
    for (int s = 1; s < 16; ++s) {
        if (st == s) {
            #pragma unroll
            for (int l = 0; l < LBL; ++l) red[px][l] += acc[l];
        }
        __syncthreads();
    }
    if (t < 16) {
        int i2 = blockIdx.x * 16 + t;
        float nb = nbi[i2];
        float ns = nsp[i2];
        float v[LBL];
        float mx = -1e30f;
        #pragma unroll
        for (int l = 0; l < LBL; ++l) {
            v[l] = -U[l * NPIX + i2] + SP[l * NPIX + i2] + BI_W_C * nb * red[t][l];
            mx = fmaxf(mx, v[l]);
        }
        float s = 0.f;
        #pragma unroll
        for (int l = 0; l < LBL; ++l) { v[l] = __expf(v[l] - mx); s += v[l]; }
        float inv = 1.f / s;
        #pragma unroll
        for (int l = 0; l < LBL; ++l) {
            float q = v[l] * inv;
            Qo[l * NPIX + i2] = q;
            Ao[l * NPIX + i2] = ns * q;
            Qto[l * NPIX + i2] = f2bf(nb * q);
        }
    }
}

// ---------------------------------------------------------------- launch
extern "C" void kernel_launch(void* const* d_in, const int* in_sizes, int n_in,
                              void* d_out, int out_size, void* d_ws, size_t ws_size,
                              hipStream_t stream) {
    const float* U = (const float*)d_in[0];
    const float* I = (const float*)d_in[1];

    char* w = (char*)d_ws;
    float* fx  = (float*)w;                 w += NPIX * sizeof(float);
    float* fy  = (float*)w;                 w += NPIX * sizeof(float);
    float* fr  = (float*)w;                 w += NPIX * sizeof(float);
    float* fg  = (float*)w;                 w += NPIX * sizeof(float);
    float* fb  = (float*)w;                 w += NPIX * sizeof(float);
    float* nsp = (float*)w;                 w += NPIX * sizeof(float);
    float* nbi = (float*)w;                 w += NPIX * sizeof(float);
    float* A   = (float*)w;                 w += (size_t)LBL * NPIX * sizeof(float);
    float* SP  = (float*)w;                 w += (size_t)LBL * NPIX * sizeof(float);
    unsigned short* Qtb[2];
    Qtb[0] = (unsigned short*)w;            w += (size_t)LPAD * NPIX * sizeof(unsigned short);
    Qtb[1] = (unsigned short*)w;            w += (size_t)LPAD * NPIX * sizeof(unsigned short);
    float* P = (float*)w;                   w += (size_t)JCH * NPIX * 32 * sizeof(float);
    unsigned short* K = (unsigned short*)w;
    size_t need = (size_t)(w - (char*)d_ws) + (size_t)NPIX * NPIX * sizeof(unsigned short);
    bool fast = (ws_size >= need);

    float* Qout = (float*)d_out;   // overwritten every iteration; final iter is the answer

    k_prep<<<(NPIX + 255) / 256, 256, 0, stream>>>(I, fx, fy, fr, fg, fb, nsp);
    if (fast) k_K<true ><<<NPIX, 256, 0, stream>>>(fx, fy, fr, fg, fb, nbi, K);
    else      k_K<false><<<NPIX, 256, 0, stream>>>(fx, fy, fr, fg, fb, nbi, nullptr);
    k_q0<<<(NPIX + 255) / 256, 256, 0, stream>>>(U, nbi, nsp, A, Qtb[0], Qtb[1]);

    for (int t = 0; t < N_ITER; ++t) {
        const unsigned short* Qtin = Qtb[t & 1];
        unsigned short* Qtout = Qtb[(t + 1) & 1];
        k_sp<<<LBL * 12, 256, 0, stream>>>(A, nsp, SP);
        if (fast) {
            k_bi_fast<<<NIT * JCH, 256, 0, stream>>>(K, Qtin, P);
            k_red<<<NPIX / 256, 256, 0, stream>>>(P, U, SP, nbi, nsp, Qout, A, Qtout);
        } else {
            k_bi_slow<<<NPIX / 16, 256, 0, stream>>>(fx, fy, fr, fg, fb, nbi, Qtin, U, SP, nsp, Qout, A, Qtout);
        }
    }
}

// Round 5
// 708.283 us; speedup vs baseline: 1.4344x; 1.1194x over previous
//
#include <hip/hip_runtime.h>
#include <hip/hip_bf16.h>
#include <stddef.h>

#define HH 96
#define WW 96
#define NPIX 9216
#define LBL 21
#define LPAD 32
#define RAD 9            // int(3 * POS_STD)
#define N_ITER 10
#define POS_W_C 3.0f
#define BI_W_C 10.0f
#define INV_XY (1.0f/80.0f)
#define INV_RGB (1.0f/13.0f)

// bilateral GEMM blocking
#define JCH 12                       // j chunks (block dimension)
#define JC (NPIX / JCH)              // 768 columns per chunk
#define JTOT (NPIX / 32)             // 288 jt-tiles per i-tile row (swizzled K)
#define ROWB (JC * 2 + 16)           // LDS row stride bytes (stride 388 words -> 2-way, free)
#define CHROW (ROWB / 16)            // 97 16B-chunks per LDS row
#define TOTCH (32 * CHROW)           // 3104 chunks to stage
#define ITILE 128                    // rows per block (4 waves x 2 subtiles x 16)
#define NITB (NPIX / ITILE)          // 72 i-blocks

typedef __bf16 bf16x8 __attribute__((ext_vector_type(8)));
typedef float  f32x4  __attribute__((ext_vector_type(4)));

// exp(-0.5*(d/3)^2), d = -9..9  (matches reference _gauss1d(3.0))
__device__ const float GK[2 * RAD + 1] = {
    0.01110900f, 0.02856548f, 0.06572886f, 0.13533528f, 0.24935220f,
    0.41111229f, 0.60653066f, 0.80073740f, 0.94595947f, 1.00000000f,
    0.94595947f, 0.80073740f, 0.60653066f, 0.41111229f, 0.24935220f,
    0.13533528f, 0.06572886f, 0.02856548f, 0.01110900f
};

__device__ __forceinline__ unsigned short f2bf(float f) {
    unsigned u = __float_as_uint(f);
    unsigned r = (u + 0x7fffu + ((u >> 16) & 1u)) >> 16;
    return (unsigned short)r;
}
__device__ __forceinline__ float bf2f(unsigned short s) {
    return __uint_as_float(((unsigned)s) << 16);
}
__device__ __forceinline__ unsigned pk2bf(float a, float b) {
    __hip_bfloat162 h = __float22bfloat162_rn(make_float2(a, b));
    return *(unsigned*)&h;
}

// ---------------------------------------------------------------- k_prep
// features (SoA), S = -0.5*|f|^2, spatial normalizer nsp
__global__ void k_prep(const float* __restrict__ I,
                       float* __restrict__ fx, float* __restrict__ fy,
                       float* __restrict__ fr, float* __restrict__ fg,
                       float* __restrict__ fb, float* __restrict__ S,
                       float* __restrict__ nsp) {
    int n = blockIdx.x * 256 + threadIdx.x;
    if (n >= NPIX) return;
    int y = n / WW, x = n % WW;
    float vx = (float)x * INV_XY;
    float vy = (float)y * INV_XY;
    float vr = I[n] * INV_RGB;
    float vg = I[NPIX + n] * INV_RGB;
    float vb = I[2 * NPIX + n] * INV_RGB;
    fx[n] = vx; fy[n] = vy; fr[n] = vr; fg[n] = vg; fb[n] = vb;
    S[n] = -0.5f * (vx*vx + vy*vy + vr*vr + vg*vg + vb*vb);
    float sy = 0.f, sx = 0.f;
    #pragma unroll
    for (int d = -RAD; d <= RAD; ++d) {
        float g = GK[d + RAD];
        if ((unsigned)(y + d) < HH) sy += g;
        if ((unsigned)(x + d) < WW) sx += g;
    }
    nsp[n] = rsqrtf(sy * sx);
}

// ---------------------------------------------------------------- k_K
// K[i][j] = exp(S_i + S_j + f_i·f_j), stored in MFMA-swizzled tile layout:
// flat = ((it*JTOT + jtile)*64 + m + 16*kh)*8 + e, i=16it+m, j=32jtile+8kh+e
template <bool STORE>
__global__ void k_K(const float* __restrict__ fx, const float* __restrict__ fy,
                    const float* __restrict__ fr, const float* __restrict__ fg,
                    const float* __restrict__ fb, const float* __restrict__ S,
                    float* __restrict__ nbi, unsigned short* __restrict__ K) {
    int i = blockIdx.x;
    int t = threadIdx.x;
    float hx = fx[i], hy = fy[i], hr = fr[i], hg = fg[i], hb = fb[i];
    float ci = S[i];
    unsigned short* Kb = K + (((size_t)(i >> 4) * JTOT) * 64 + (i & 15)) * 8;
    float sum = 0.f;
    for (int jt = t; jt < NPIX / 4; jt += 256) {
        int j = jt * 4;
        float4 vx = *(const float4*)(fx + j);
        float4 vy = *(const float4*)(fy + j);
        float4 vr = *(const float4*)(fr + j);
        float4 vg = *(const float4*)(fg + j);
        float4 vb = *(const float4*)(fb + j);
        float4 vs = *(const float4*)(S + j);
        float k0, k1, k2, k3;
        {
            float v = ci + vs.x + hx*vx.x + hy*vy.x + hr*vr.x + hg*vg.x + hb*vb.x;
            k0 = __expf(v);
        }
        {
            float v = ci + vs.y + hx*vx.y + hy*vy.y + hr*vr.y + hg*vg.y + hb*vb.y;
            k1 = __expf(v);
        }
        {
            float v = ci + vs.z + hx*vx.z + hy*vy.z + hr*vr.z + hg*vg.z + hb*vb.z;
            k2 = __expf(v);
        }
        {
            float v = ci + vs.w + hx*vx.w + hy*vy.w + hr*vr.w + hg*vg.w + hb*vb.w;
            k3 = __expf(v);
        }
        sum += (k0 + k1) + (k2 + k3);
        if (STORE) {
            uint2 u;
            u.x = pk2bf(k0, k1);
            u.y = pk2bf(k2, k3);
            int jtile = j >> 5, kh = (j >> 3) & 3, e = j & 7;  // e in {0,4}
            *(uint2*)(Kb + (size_t)jtile * 512 + kh * 128 + e) = u;
        }
    }
    __shared__ float red[256];
    red[t] = sum;
    __syncthreads();
    #pragma unroll
    for (int s = 128; s > 0; s >>= 1) {
        if (t < s) red[t] += red[t + s];
        __syncthreads();
    }
    if (t == 0) nbi[i] = rsqrtf(red[0]);
}

// ---------------------------------------------------------------- k_q0
__global__ void k_q0(const float* __restrict__ U, const float* __restrict__ nbi,
                     const float* __restrict__ nsp, float* __restrict__ A,
                     unsigned short* __restrict__ Qt0, unsigned short* __restrict__ Qt1) {
    int n = blockIdx.x * 256 + threadIdx.x;
    if (n >= NPIX) return;
    float v[LBL];
    float mx = -1e30f;
    #pragma unroll
    for (int l = 0; l < LBL; ++l) { v[l] = -U[l * NPIX + n]; mx = fmaxf(mx, v[l]); }
    float s = 0.f;
    #pragma unroll
    for (int l = 0; l < LBL; ++l) { v[l] = __expf(v[l] - mx); s += v[l]; }
    float inv = 1.f / s;
    float nb = nbi[n];
    float ns = nsp[n];
    #pragma unroll
    for (int l = 0; l < LBL; ++l) {
        float q = v[l] * inv;
        A[l * NPIX + n] = ns * q;
        Qt0[l * NPIX + n] = f2bf(nb * q);
    }
    #pragma unroll
    for (int l = LBL; l < LPAD; ++l) { Qt0[l * NPIX + n] = 0; Qt1[l * NPIX + n] = 0; }
}

// ---------------------------------------------------------------- k_sp
// fused separable conv, one block per (label, 4-row band): 504 blocks
__global__ void k_sp(const float* __restrict__ A, const float* __restrict__ nsp,
                     float* __restrict__ SP) {
    __shared__ float ty[4][WW];
    int l = blockIdx.x / 24;
    int y0 = (blockIdx.x % 24) * 4;
    int t = threadIdx.x;
    const float* Al = A + (size_t)l * NPIX;
    #pragma unroll
    for (int c = 0; c < 2; ++c) {
        int p = t + c * 256;          // 0..383
        if (p < 4 * WW) {
            int yy = p / WW, x = p % WW;
            int y = y0 + yy;
            float s = 0.f;
            #pragma unroll
            for (int d = -RAD; d <= RAD; ++d) {
                int yd = y + d;
                if ((unsigned)yd < HH) s += GK[d + RAD] * Al[yd * WW + x];
            }
            ty[yy][x] = s;
        }
    }
    __syncthreads();
    #pragma unroll
    for (int c = 0; c < 2; ++c) {
        int p = t + c * 256;
        if (p < 4 * WW) {
            int yy = p / WW, x = p % WW;
            float s = 0.f;
            #pragma unroll
            for (int d = -RAD; d <= RAD; ++d) {
                int xd = x + d;
                if ((unsigned)xd < WW) s += GK[d + RAD] * ty[yy][xd];
            }
            int pp = (y0 + yy) * WW + x;
            SP[(size_t)l * NPIX + pp] = POS_W_C * nsp[pp] * s;
        }
    }
}

// ---------------------------------------------------------------- k_bi_fast
// grid = NITB*JCH. Block: stage Qt[32][768] into LDS; 4 waves x 2 i-subtiles
// (128 rows total); K in swizzled layout -> contiguous 1KB wave loads.
// Partials P[jc][i][0..23] fp32.
__global__ void __launch_bounds__(256)
k_bi_fast(const unsigned short* __restrict__ K, const unsigned short* __restrict__ Qt,
          float* __restrict__ P) {
    __shared__ __align__(16) unsigned short Bsh[32 * ROWB / 2];  // 49,664 B
    int tid = threadIdx.x;
    int bid = blockIdx.x;
    int jc  = bid / NITB;          // 0..11
    int itb = bid % NITB;          // 0..71
    int base_j = jc * JC;
    int jtb = jc * (JC / 32);      // first jt-tile of this chunk

    // ---- stage Qt chunk
    for (int itn = 0; itn < (TOTCH + 255) / 256; ++itn) {
        int c = itn * 256 + tid;
        if (c < TOTCH) {
            int l = c / CHROW;
            int off = c - l * CHROW;                  // 0..96
            int off16 = (off == CHROW - 1) ? 0 : off; // pad chunk: never read
            uint4 v = *(const uint4*)(Qt + (size_t)l * NPIX + base_j + off16 * 8);
            *((uint4*)Bsh + c) = v;
        }
    }
    __syncthreads();

    int lane = tid & 63;
    int wv = tid >> 6;      // 0..3
    int m  = lane & 15;
    int kh = lane >> 4;

    const bf16x8* pa0 = (const bf16x8*)K + ((size_t)(itb * 8 + wv)     * JTOT + jtb) * 64 + lane;
    const bf16x8* pa1 = (const bf16x8*)K + ((size_t)(itb * 8 + 4 + wv) * JTOT + jtb) * 64 + lane;
    const char* lb0 = (const char*)Bsh + m * ROWB + kh * 16;
    const char* lb1 = (const char*)Bsh + (m + 16) * ROWB + kh * 16;

    f32x4 acc00 = {0.f,0.f,0.f,0.f}, acc01 = {0.f,0.f,0.f,0.f};
    f32x4 acc10 = {0.f,0.f,0.f,0.f}, acc11 = {0.f,0.f,0.f,0.f};

    #pragma unroll 4
    for (int jt = 0; jt < JC / 32; ++jt) {     // 24 iters
        bf16x8 a0 = pa0[jt * 64];
        bf16x8 a1 = pa1[jt * 64];
        bf16x8 b0 = *(const bf16x8*)(lb0 + jt * 64);
        bf16x8 b1 = *(const bf16x8*)(lb1 + jt * 64);
        acc00 = __builtin_amdgcn_mfma_f32_16x16x32_bf16(a0, b0, acc00, 0, 0, 0);
        acc01 = __builtin_amdgcn_mfma_f32_16x16x32_bf16(a0, b1, acc01, 0, 0, 0);
        acc10 = __builtin_amdgcn_mfma_f32_16x16x32_bf16(a1, b0, acc10, 0, 0, 0);
        acc11 = __builtin_amdgcn_mfma_f32_16x16x32_bf16(a1, b1, acc11, 0, 0, 0);
    }

    // partials; C/D layout col(label)=m, row=kh*4+r
    float* Pp = P + (size_t)jc * NPIX * 32;
    int i0 = itb * 128 + wv * 16 + kh * 4;
    int i1 = i0 + 64;
    #pragma unroll
    for (int r = 0; r < 4; ++r) {
        Pp[(size_t)(i0 + r) * 32 + m] = acc00[r];
        Pp[(size_t)(i1 + r) * 32 + m] = acc10[r];
        if (m < 8) {
            Pp[(size_t)(i0 + r) * 32 + 16 + m] = acc01[r];
            Pp[(size_t)(i1 + r) * 32 + 16 + m] = acc11[r];
        }
    }
}

// ---------------------------------------------------------------- k_red
// 288 blocks x 64 threads; half-wave jc-split + shfl merge; fused softmax.
__global__ void __launch_bounds__(64)
k_red(const float* __restrict__ P, const float* __restrict__ U,
      const float* __restrict__ SP, const float* __restrict__ nbi,
      const float* __restrict__ nsp,
      float* __restrict__ Qo, float* __restrict__ Ao,
      unsigned short* __restrict__ Qto) {
    int lane = threadIdx.x;
    int p = blockIdx.x * 32 + (lane & 31);
    int h = lane >> 5;                 // 0: jc 0-5, 1: jc 6-11
    float4 s[6] = {{0,0,0,0},{0,0,0,0},{0,0,0,0},{0,0,0,0},{0,0,0,0},{0,0,0,0}};
    #pragma unroll
    for (int jj = 0; jj < 6; ++jj) {
        int jcc = h * 6 + jj;
        const float4* pp = (const float4*)(P + ((size_t)jcc * NPIX + p) * 32);
        #pragma unroll
        for (int q = 0; q < 6; ++q) s[q] += pp[q];
    }
    float bi[24];
    #pragma unroll
    for (int q = 0; q < 6; ++q) {
        bi[4*q+0] = s[q].x + __shfl_down(s[q].x, 32);
        bi[4*q+1] = s[q].y + __shfl_down(s[q].y, 32);
        bi[4*q+2] = s[q].z + __shfl_down(s[q].z, 32);
        bi[4*q+3] = s[q].w + __shfl_down(s[q].w, 32);
    }
    if (h) return;

    float nb = nbi[p];
    float ns = nsp[p];
    float v[LBL];
    float mx = -1e30f;
    #pragma unroll
    for (int l = 0; l < LBL; ++l) {
        v[l] = -U[l * NPIX + p] + SP[l * NPIX + p] + BI_W_C * nb * bi[l];
        mx = fmaxf(mx, v[l]);
    }
    float ssum = 0.f;
    #pragma unroll
    for (int l = 0; l < LBL; ++l) { v[l] = __expf(v[l] - mx); ssum += v[l]; }
    float inv = 1.f / ssum;
    #pragma unroll
    for (int l = 0; l < LBL; ++l) {
        float q = v[l] * inv;
        Qo[l * NPIX + p] = q;
        Ao[l * NPIX + p] = ns * q;
        Qto[l * NPIX + p] = f2bf(nb * q);
    }
}

// ---------------------------------------------------------------- k_bi_slow
// fallback when ws too small for K (correct but slow)
__global__ void k_bi_slow(const float* __restrict__ fx, const float* __restrict__ fy,
                          const float* __restrict__ fr, const float* __restrict__ fg,
                          const float* __restrict__ fb,
                          const float* __restrict__ nbi, const unsigned short* __restrict__ Qt,
                          const float* __restrict__ U, const float* __restrict__ SP,
                          const float* __restrict__ nsp,
                          float* __restrict__ Qo, float* __restrict__ Ao,
                          unsigned short* __restrict__ Qto) {
    int t = threadIdx.x;
    int px = t & 15, st = t >> 4;
    int i = blockIdx.x * 16 + px;
    float xi = fx[i], yi = fy[i], ri = fr[i], gi = fg[i], bi = fb[i];
    float acc[LBL];
    #pragma unroll
    for (int l = 0; l < LBL; ++l) acc[l] = 0.f;
    int j0 = st * (NPIX / 16);
    for (int j = j0; j < j0 + NPIX / 16; ++j) {
        float dx = xi - fx[j], dy = yi - fy[j];
        float dr = ri - fr[j], dg = gi - fg[j], db = bi - fb[j];
        float D = dx*dx + dy*dy + dr*dr + dg*dg + db*db;
        float w = __expf(-0.5f * D);
        #pragma unroll
        for (int l = 0; l < LBL; ++l) acc[l] += w * bf2f(Qt[l * NPIX + j]);
    }
    __shared__ float red[16][LBL];
    if (st == 0) {
        #pragma unroll
        for (int l = 0; l < LBL; ++l) red[px][l] = acc[l];
    }
    __syncthreads();
    for (int s = 1; s < 16; ++s) {
        if (st == s) {
            #pragma unroll
            for (int l = 0; l < LBL; ++l) red[px][l] += acc[l];
        }
        __syncthreads();
    }
    if (t < 16) {
        int i2 = blockIdx.x * 16 + t;
        float nb = nbi[i2];
        float ns = nsp[i2];
        float v[LBL];
        float mx = -1e30f;
        #pragma unroll
        for (int l = 0; l < LBL; ++l) {
            v[l] = -U[l * NPIX + i2] + SP[l * NPIX + i2] + BI_W_C * nb * red[t][l];
            mx = fmaxf(mx, v[l]);
        }
        float s = 0.f;
        #pragma unroll
        for (int l = 0; l < LBL; ++l) { v[l] = __expf(v[l] - mx); s += v[l]; }
        float inv = 1.f / s;
        #pragma unroll
        for (int l = 0; l < LBL; ++l) {
            float q = v[l] * inv;
            Qo[l * NPIX + i2] = q;
            Ao[l * NPIX + i2] = ns * q;
            Qto[l * NPIX + i2] = f2bf(nb * q);
        }
    }
}

// ---------------------------------------------------------------- launch
extern "C" void kernel_launch(void* const* d_in, const int* in_sizes, int n_in,
                              void* d_out, int out_size, void* d_ws, size_t ws_size,
                              hipStream_t stream) {
    const float* U = (const float*)d_in[0];
    const float* I = (const float*)d_in[1];

    char* w = (char*)d_ws;
    float* fx  = (float*)w;                 w += NPIX * sizeof(float);
    float* fy  = (float*)w;                 w += NPIX * sizeof(float);
    float* fr  = (float*)w;                 w += NPIX * sizeof(float);
    float* fg  = (float*)w;                 w += NPIX * sizeof(float);
    float* fb  = (float*)w;                 w += NPIX * sizeof(float);
    float* S   = (float*)w;                 w += NPIX * sizeof(float);
    float* nsp = (float*)w;                 w += NPIX * sizeof(float);
    float* nbi = (float*)w;                 w += NPIX * sizeof(float);
    float* A   = (float*)w;                 w += (size_t)LBL * NPIX * sizeof(float);
    float* SP  = (float*)w;                 w += (size_t)LBL * NPIX * sizeof(float);
    unsigned short* Qtb[2];
    Qtb[0] = (unsigned short*)w;            w += (size_t)LPAD * NPIX * sizeof(unsigned short);
    Qtb[1] = (unsigned short*)w;            w += (size_t)LPAD * NPIX * sizeof(unsigned short);
    float* P = (float*)w;                   w += (size_t)JCH * NPIX * 32 * sizeof(float);
    unsigned short* K = (unsigned short*)w;
    size_t need = (size_t)(w - (char*)d_ws) + (size_t)NPIX * NPIX * sizeof(unsigned short);
    bool fast = (ws_size >= need);

    float* Qout = (float*)d_out;   // overwritten every iteration; final iter is the answer

    k_prep<<<(NPIX + 255) / 256, 256, 0, stream>>>(I, fx, fy, fr, fg, fb, S, nsp);
    if (fast) k_K<true ><<<NPIX, 256, 0, stream>>>(fx, fy, fr, fg, fb, S, nbi, K);
    else      k_K<false><<<NPIX, 256, 0, stream>>>(fx, fy, fr, fg, fb, S, nbi, nullptr);
    k_q0<<<(NPIX + 255) / 256, 256, 0, stream>>>(U, nbi, nsp, A, Qtb[0], Qtb[1]);

    for (int t = 0; t < N_ITER; ++t) {
        const unsigned short* Qtin = Qtb[t & 1];
        unsigned short* Qtout = Qtb[(t + 1) & 1];
        k_sp<<<LBL * 24, 256, 0, stream>>>(A, nsp, SP);
        if (fast) {
            k_bi_fast<<<NITB * JCH, 256, 0, stream>>>(K, Qtin, P);
            k_red<<<NPIX / 32, 64, 0, stream>>>(P, U, SP, nbi, nsp, Qout, A, Qtout);
        } else {
            k_bi_slow<<<NPIX / 16, 256, 0, stream>>>(fx, fy, fr, fg, fb, nbi, Qtin, U, SP, nsp, Qout, A, Qtout);
        }
    }
}

// Round 6
// 554.513 us; speedup vs baseline: 1.8321x; 1.2773x over previous
//
#include <hip/hip_runtime.h>
#include <hip/hip_bf16.h>
#include <stddef.h>

#define HH 96
#define WW 96
#define NPIX 9216
#define LBL 21
#define LPAD 32
#define RAD 9            // int(3 * POS_STD)
#define N_ITER 10
#define POS_W_C 3.0f
#define BI_W_C 10.0f
#define INV_XY (1.0f/80.0f)
#define INV_RGB (1.0f/13.0f)

// bilateral GEMM blocking
#define JCH 12                       // j chunks (block dimension)
#define JC (NPIX / JCH)              // 768 columns per chunk
#define JTOT (NPIX / 32)             // 288 jt-tiles (swizzled K)
#define ROWB (JC * 2 + 16)           // LDS row stride bytes
#define CHROW (ROWB / 16)            // 97 16B-chunks per LDS row
#define TOTCH (32 * CHROW)           // 3104 chunks to stage
#define ITILE 128                    // rows per block (4 waves x 2 subtiles x 16)
#define NITB (NPIX / ITILE)          // 72 i-blocks
#define NSPB (LBL * 24)              // 504 conv bands (4 rows each)

typedef __bf16 bf16x8 __attribute__((ext_vector_type(8)));
typedef float  f32x4  __attribute__((ext_vector_type(4)));

// exp(-0.5*(d/3)^2), d = -9..9  (matches reference _gauss1d(3.0))
__device__ const float GK[2 * RAD + 1] = {
    0.01110900f, 0.02856548f, 0.06572886f, 0.13533528f, 0.24935220f,
    0.41111229f, 0.60653066f, 0.80073740f, 0.94595947f, 1.00000000f,
    0.94595947f, 0.80073740f, 0.60653066f, 0.41111229f, 0.24935220f,
    0.13533528f, 0.06572886f, 0.02856548f, 0.01110900f
};

__device__ __forceinline__ unsigned short f2bf(float f) {
    unsigned u = __float_as_uint(f);
    unsigned r = (u + 0x7fffu + ((u >> 16) & 1u)) >> 16;
    return (unsigned short)r;
}
__device__ __forceinline__ float bf2f(unsigned short s) {
    return __uint_as_float(((unsigned)s) << 16);
}
__device__ __forceinline__ unsigned pk2bf(float a, float b) {
    __hip_bfloat162 h = __float22bfloat162_rn(make_float2(a, b));
    return *(unsigned*)&h;
}

// ---------------------------------------------------------------- k_prep
__global__ void k_prep(const float* __restrict__ I,
                       float* __restrict__ fx, float* __restrict__ fy,
                       float* __restrict__ fr, float* __restrict__ fg,
                       float* __restrict__ fb, float* __restrict__ S,
                       float* __restrict__ nsp) {
    int n = blockIdx.x * 256 + threadIdx.x;
    if (n >= NPIX) return;
    int y = n / WW, x = n % WW;
    float vx = (float)x * INV_XY;
    float vy = (float)y * INV_XY;
    float vr = I[n] * INV_RGB;
    float vg = I[NPIX + n] * INV_RGB;
    float vb = I[2 * NPIX + n] * INV_RGB;
    fx[n] = vx; fy[n] = vy; fr[n] = vr; fg[n] = vg; fb[n] = vb;
    S[n] = -0.5f * (vx*vx + vy*vy + vr*vr + vg*vg + vb*vb);
    float sy = 0.f, sx = 0.f;
    #pragma unroll
    for (int d = -RAD; d <= RAD; ++d) {
        float g = GK[d + RAD];
        if ((unsigned)(y + d) < HH) sy += g;
        if ((unsigned)(x + d) < WW) sx += g;
    }
    nsp[n] = rsqrtf(sy * sx);
}

// ---------------------------------------------------------------- k_K
// one block per 16-row i-tile. Thread owns slot (tid&63) of jtile pass*4+(tid>>6):
// computes 8 consecutive j, stores one uint4 -> 4KB contiguous per pass.
// Layout (matches k_bi A-frag): flat = ((it*JTOT + jtile)*64 + m + 16*kh)*8 + e,
// i = 16it + m, j = 32*jtile + 8*kh + e.
template <bool STORE>
__global__ void __launch_bounds__(256)
k_K(const float* __restrict__ fx, const float* __restrict__ fy,
    const float* __restrict__ fr, const float* __restrict__ fg,
    const float* __restrict__ fb, const float* __restrict__ S,
    float* __restrict__ nbi, unsigned short* __restrict__ K) {
    int it = blockIdx.x;
    int tid = threadIdx.x;
    int m = tid & 15;
    int g = tid >> 4;        // ts*4 + khs
    int khs = g & 3;
    int ts = g >> 2;
    int i = it * 16 + m;
    float hx = fx[i], hy = fy[i], hr = fr[i], hg = fg[i], hb = fb[i];
    float ci = S[i];
    unsigned short* Kb = K + (size_t)it * JTOT * 512;
    float sum = 0.f;
    for (int pass = 0; pass < JTOT / 4; ++pass) {
        int jtile = pass * 4 + ts;
        int j = jtile * 32 + khs * 8;
        float4 x0 = *(const float4*)(fx + j), x1 = *(const float4*)(fx + j + 4);
        float4 y0 = *(const float4*)(fy + j), y1 = *(const float4*)(fy + j + 4);
        float4 r0 = *(const float4*)(fr + j), r1 = *(const float4*)(fr + j + 4);
        float4 g0 = *(const float4*)(fg + j), g1 = *(const float4*)(fg + j + 4);
        float4 b0 = *(const float4*)(fb + j), b1 = *(const float4*)(fb + j + 4);
        float4 s0 = *(const float4*)(S + j),  s1 = *(const float4*)(S + j + 4);
        float k0 = __expf(ci + s0.x + hx*x0.x + hy*y0.x + hr*r0.x + hg*g0.x + hb*b0.x);
        float k1 = __expf(ci + s0.y + hx*x0.y + hy*y0.y + hr*r0.y + hg*g0.y + hb*b0.y);
        float k2 = __expf(ci + s0.z + hx*x0.z + hy*y0.z + hr*r0.z + hg*g0.z + hb*b0.z);
        float k3 = __expf(ci + s0.w + hx*x0.w + hy*y0.w + hr*r0.w + hg*g0.w + hb*b0.w);
        float k4 = __expf(ci + s1.x + hx*x1.x + hy*y1.x + hr*r1.x + hg*g1.x + hb*b1.x);
        float k5 = __expf(ci + s1.y + hx*x1.y + hy*y1.y + hr*r1.y + hg*g1.y + hb*b1.y);
        float k6 = __expf(ci + s1.z + hx*x1.z + hy*y1.z + hr*r1.z + hg*g1.z + hb*b1.z);
        float k7 = __expf(ci + s1.w + hx*x1.w + hy*y1.w + hr*r1.w + hg*g1.w + hb*b1.w);
        sum += ((k0 + k1) + (k2 + k3)) + ((k4 + k5) + (k6 + k7));
        if (STORE) {
            uint4 u;
            u.x = pk2bf(k0, k1);
            u.y = pk2bf(k2, k3);
            u.z = pk2bf(k4, k5);
            u.w = pk2bf(k6, k7);
            *(uint4*)(Kb + (size_t)jtile * 512 + (tid & 63) * 8) = u;
        }
    }
    __shared__ float red[16][17];
    red[g][m] = sum;
    __syncthreads();
    if (tid < 16) {
        float tot = 0.f;
        #pragma unroll
        for (int q = 0; q < 16; ++q) tot += red[q][tid];
        nbi[it * 16 + tid] = rsqrtf(tot);
    }
}

// ---------------------------------------------------------------- k_q0
__global__ void k_q0(const float* __restrict__ U, const float* __restrict__ nbi,
                     const float* __restrict__ nsp, float* __restrict__ A,
                     unsigned short* __restrict__ Qt0, unsigned short* __restrict__ Qt1) {
    int n = blockIdx.x * 256 + threadIdx.x;
    if (n >= NPIX) return;
    float v[LBL];
    float mx = -1e30f;
    #pragma unroll
    for (int l = 0; l < LBL; ++l) { v[l] = -U[l * NPIX + n]; mx = fmaxf(mx, v[l]); }
    float s = 0.f;
    #pragma unroll
    for (int l = 0; l < LBL; ++l) { v[l] = __expf(v[l] - mx); s += v[l]; }
    float inv = 1.f / s;
    float nb = nbi[n];
    float ns = nsp[n];
    #pragma unroll
    for (int l = 0; l < LBL; ++l) {
        float q = v[l] * inv;
        A[l * NPIX + n] = ns * q;
        Qt0[l * NPIX + n] = f2bf(nb * q);
    }
    #pragma unroll
    for (int l = LBL; l < LPAD; ++l) { Qt0[l * NPIX + n] = 0; Qt1[l * NPIX + n] = 0; }
}

// ---------------------------------------------------------------- k_sp
// slow-path only. SP = POS_W * nsp * Gx(Gy(A)) - U
__global__ void k_sp(const float* __restrict__ A, const float* __restrict__ nsp,
                     const float* __restrict__ U, float* __restrict__ SP) {
    __shared__ float ty[4 * WW];
    int l = blockIdx.x / 24;
    int y0 = (blockIdx.x % 24) * 4;
    int t = threadIdx.x;
    const float* Al = A + (size_t)l * NPIX;
    #pragma unroll
    for (int c = 0; c < 2; ++c) {
        int p = t + c * 256;
        if (p < 4 * WW) {
            int yy = p / WW, x = p % WW;
            int y = y0 + yy;
            float s = 0.f;
            #pragma unroll
            for (int d = -RAD; d <= RAD; ++d) {
                int yd = y + d;
                if ((unsigned)yd < HH) s += GK[d + RAD] * Al[yd * WW + x];
            }
            ty[p] = s;
        }
    }
    __syncthreads();
    #pragma unroll
    for (int c = 0; c < 2; ++c) {
        int p = t + c * 256;
        if (p < 4 * WW) {
            int yy = p / WW, x = p % WW;
            float s = 0.f;
            #pragma unroll
            for (int d = -RAD; d <= RAD; ++d) {
                int xd = x + d;
                if ((unsigned)xd < WW) s += GK[d + RAD] * ty[yy * WW + xd];
            }
            int pp = (y0 + yy) * WW + x;
            SP[(size_t)l * NPIX + pp] = POS_W_C * nsp[pp] * s - U[(size_t)l * NPIX + pp];
        }
    }
}

// ---------------------------------------------------------------- k_bi_fast
// grid = NITB*JCH = 864. Blocks 0..503 additionally run one spatial-conv band
// (reusing Bsh LDS) before staging. Then: stage Qt[32][768] into LDS; 4 waves
// x 2 i-subtiles (128 rows); K swizzled -> contiguous 1KB wave loads.
__global__ void __launch_bounds__(256)
k_bi_fast(const unsigned short* __restrict__ K, const unsigned short* __restrict__ Qt,
          const float* __restrict__ A, const float* __restrict__ nsp,
          const float* __restrict__ U, float* __restrict__ SP,
          float* __restrict__ P) {
    __shared__ __align__(16) unsigned short Bsh[32 * ROWB / 2];  // 49,664 B
    int tid = threadIdx.x;
    int bid = blockIdx.x;

    // ---- fused spatial conv band (blocks 0..503)
    if (bid < NSPB) {
        float* ty = (float*)Bsh;   // 4*96 floats = 1536 B
        int l = bid / 24;
        int y0b = (bid % 24) * 4;
        const float* Al = A + (size_t)l * NPIX;
        #pragma unroll
        for (int c = 0; c < 2; ++c) {
            int p = tid + c * 256;
            if (p < 4 * WW) {
                int yy = p / WW, x = p % WW;
                int y = y0b + yy;
                float s = 0.f;
                #pragma unroll
                for (int d = -RAD; d <= RAD; ++d) {
                    int yd = y + d;
                    if ((unsigned)yd < HH) s += GK[d + RAD] * Al[yd * WW + x];
                }
                ty[p] = s;
            }
        }
        __syncthreads();
        #pragma unroll
        for (int c = 0; c < 2; ++c) {
            int p = tid + c * 256;
            if (p < 4 * WW) {
                int yy = p / WW, x = p % WW;
                float s = 0.f;
                #pragma unroll
                for (int d = -RAD; d <= RAD; ++d) {
                    int xd = x + d;
                    if ((unsigned)xd < WW) s += GK[d + RAD] * ty[yy * WW + xd];
                }
                int pp = (y0b + yy) * WW + x;
                SP[(size_t)l * NPIX + pp] = POS_W_C * nsp[pp] * s - U[(size_t)l * NPIX + pp];
            }
        }
        __syncthreads();
    }

    int jc  = bid / NITB;          // 0..11
    int itb = bid % NITB;          // 0..71
    int base_j = jc * JC;
    int jtb = jc * (JC / 32);

    // ---- stage Qt chunk
    for (int itn = 0; itn < (TOTCH + 255) / 256; ++itn) {
        int c = itn * 256 + tid;
        if (c < TOTCH) {
            int l = c / CHROW;
            int off = c - l * CHROW;
            int off16 = (off == CHROW - 1) ? 0 : off; // pad chunk: never read
            uint4 v = *(const uint4*)(Qt + (size_t)l * NPIX + base_j + off16 * 8);
            *((uint4*)Bsh + c) = v;
        }
    }
    __syncthreads();

    int lane = tid & 63;
    int wv = tid >> 6;
    int m  = lane & 15;
    int kh = lane >> 4;

    const bf16x8* pa0 = (const bf16x8*)K + ((size_t)(itb * 8 + wv)     * JTOT + jtb) * 64 + lane;
    const bf16x8* pa1 = (const bf16x8*)K + ((size_t)(itb * 8 + 4 + wv) * JTOT + jtb) * 64 + lane;
    const char* lb0 = (const char*)Bsh + m * ROWB + kh * 16;
    const char* lb1 = (const char*)Bsh + (m + 16) * ROWB + kh * 16;

    f32x4 acc00 = {0.f,0.f,0.f,0.f}, acc01 = {0.f,0.f,0.f,0.f};
    f32x4 acc10 = {0.f,0.f,0.f,0.f}, acc11 = {0.f,0.f,0.f,0.f};

    #pragma unroll 4
    for (int jt = 0; jt < JC / 32; ++jt) {     // 24 iters
        bf16x8 a0 = pa0[jt * 64];
        bf16x8 a1 = pa1[jt * 64];
        bf16x8 b0 = *(const bf16x8*)(lb0 + jt * 64);
        bf16x8 b1 = *(const bf16x8*)(lb1 + jt * 64);
        acc00 = __builtin_amdgcn_mfma_f32_16x16x32_bf16(a0, b0, acc00, 0, 0, 0);
        acc01 = __builtin_amdgcn_mfma_f32_16x16x32_bf16(a0, b1, acc01, 0, 0, 0);
        acc10 = __builtin_amdgcn_mfma_f32_16x16x32_bf16(a1, b0, acc10, 0, 0, 0);
        acc11 = __builtin_amdgcn_mfma_f32_16x16x32_bf16(a1, b1, acc11, 0, 0, 0);
    }

    float* Pp = P + (size_t)jc * NPIX * 32;
    int i0 = itb * 128 + wv * 16 + kh * 4;
    int i1 = i0 + 64;
    #pragma unroll
    for (int r = 0; r < 4; ++r) {
        Pp[(size_t)(i0 + r) * 32 + m] = acc00[r];
        Pp[(size_t)(i1 + r) * 32 + m] = acc10[r];
        if (m < 8) {
            Pp[(size_t)(i0 + r) * 32 + 16 + m] = acc01[r];
            Pp[(size_t)(i1 + r) * 32 + 16 + m] = acc11[r];
        }
    }
}

// ---------------------------------------------------------------- k_red
__global__ void __launch_bounds__(64)
k_red(const float* __restrict__ P, const float* __restrict__ SP,
      const float* __restrict__ nbi, const float* __restrict__ nsp,
      float* __restrict__ Qo, float* __restrict__ Ao,
      unsigned short* __restrict__ Qto) {
    int lane = threadIdx.x;
    int p = blockIdx.x * 32 + (lane & 31);
    int h = lane >> 5;
    float4 s[6] = {{0,0,0,0},{0,0,0,0},{0,0,0,0},{0,0,0,0},{0,0,0,0},{0,0,0,0}};
    #pragma unroll
    for (int jj = 0; jj < 6; ++jj) {
        int jcc = h * 6 + jj;
        const float4* pp = (const float4*)(P + ((size_t)jcc * NPIX + p) * 32);
        #pragma unroll
        for (int q = 0; q < 6; ++q) s[q] += pp[q];
    }
    float bi[24];
    #pragma unroll
    for (int q = 0; q < 6; ++q) {
        bi[4*q+0] = s[q].x + __shfl_down(s[q].x, 32);
        bi[4*q+1] = s[q].y + __shfl_down(s[q].y, 32);
        bi[4*q+2] = s[q].z + __shfl_down(s[q].z, 32);
        bi[4*q+3] = s[q].w + __shfl_down(s[q].w, 32);
    }
    if (h) return;

    float nb = nbi[p];
    float ns = nsp[p];
    float v[LBL];
    float mx = -1e30f;
    #pragma unroll
    for (int l = 0; l < LBL; ++l) {
        v[l] = SP[l * NPIX + p] + BI_W_C * nb * bi[l];
        mx = fmaxf(mx, v[l]);
    }
    float ssum = 0.f;
    #pragma unroll
    for (int l = 0; l < LBL; ++l) { v[l] = __expf(v[l] - mx); ssum += v[l]; }
    float inv = 1.f / ssum;
    #pragma unroll
    for (int l = 0; l < LBL; ++l) {
        float q = v[l] * inv;
        Qo[l * NPIX + p] = q;
        Ao[l * NPIX + p] = ns * q;
        Qto[l * NPIX + p] = f2bf(nb * q);
    }
}

// ---------------------------------------------------------------- k_bi_slow
__global__ void k_bi_slow(const float* __restrict__ fx, const float* __restrict__ fy,
                          const float* __restrict__ fr, const float* __restrict__ fg,
                          const float* __restrict__ fb,
                          const float* __restrict__ nbi, const unsigned short* __restrict__ Qt,
                          const float* __restrict__ SP, const float* __restrict__ nsp,
                          float* __restrict__ Qo, float* __restrict__ Ao,
                          unsigned short* __restrict__ Qto) {
    int t = threadIdx.x;
    int px = t & 15, st = t >> 4;
    int i = blockIdx.x * 16 + px;
    float xi = fx[i], yi = fy[i], ri = fr[i], gi = fg[i], bi = fb[i];
    float acc[LBL];
    #pragma unroll
    for (int l = 0; l < LBL; ++l) acc[l] = 0.f;
    int j0 = st * (NPIX / 16);
    for (int j = j0; j < j0 + NPIX / 16; ++j) {
        float dx = xi - fx[j], dy = yi - fy[j];
        float dr = ri - fr[j], dg = gi - fg[j], db = bi - fb[j];
        float D = dx*dx + dy*dy + dr*dr + dg*dg + db*db;
        float w = __expf(-0.5f * D);
        #pragma unroll
        for (int l = 0; l < LBL; ++l) acc[l] += w * bf2f(Qt[l * NPIX + j]);
    }
    __shared__ float red[16][LBL];
    if (st == 0) {
        #pragma unroll
        for (int l = 0; l < LBL; ++l) red[px][l] = acc[l];
    }
    __syncthreads();
    for (int s = 1; s < 16; ++s) {
        if (st == s) {
            #pragma unroll
            for (int l = 0; l < LBL; ++l) red[px][l] += acc[l];
        }
        __syncthreads();
    }
    if (t < 16) {
        int i2 = blockIdx.x * 16 + t;
        float nb = nbi[i2];
        float ns = nsp[i2];
        float v[LBL];
        float mx = -1e30f;
        #pragma unroll
        for (int l = 0; l < LBL; ++l) {
            v[l] = SP[l * NPIX + i2] + BI_W_C * nb * red[t][l];
            mx = fmaxf(mx, v[l]);
        }
        float s = 0.f;
        #pragma unroll
        for (int l = 0; l < LBL; ++l) { v[l] = __expf(v[l] - mx); s += v[l]; }
        float inv = 1.f / s;
        #pragma unroll
        for (int l = 0; l < LBL; ++l) {
            float q = v[l] * inv;
            Qo[l * NPIX + i2] = q;
            Ao[l * NPIX + i2] = ns * q;
            Qto[l * NPIX + i2] = f2bf(nb * q);
        }
    }
}

// ---------------------------------------------------------------- launch
extern "C" void kernel_launch(void* const* d_in, const int* in_sizes, int n_in,
                              void* d_out, int out_size, void* d_ws, size_t ws_size,
                              hipStream_t stream) {
    const float* U = (const float*)d_in[0];
    const float* I = (const float*)d_in[1];

    char* w = (char*)d_ws;
    float* fx  = (float*)w;                 w += NPIX * sizeof(float);
    float* fy  = (float*)w;                 w += NPIX * sizeof(float);
    float* fr  = (float*)w;                 w += NPIX * sizeof(float);
    float* fg  = (float*)w;                 w += NPIX * sizeof(float);
    float* fb  = (float*)w;                 w += NPIX * sizeof(float);
    float* S   = (float*)w;                 w += NPIX * sizeof(float);
    float* nsp = (float*)w;                 w += NPIX * sizeof(float);
    float* nbi = (float*)w;                 w += NPIX * sizeof(float);
    float* A   = (float*)w;                 w += (size_t)LBL * NPIX * sizeof(float);
    float* SP  = (float*)w;                 w += (size_t)LBL * NPIX * sizeof(float);
    unsigned short* Qtb[2];
    Qtb[0] = (unsigned short*)w;            w += (size_t)LPAD * NPIX * sizeof(unsigned short);
    Qtb[1] = (unsigned short*)w;            w += (size_t)LPAD * NPIX * sizeof(unsigned short);
    float* P = (float*)w;                   w += (size_t)JCH * NPIX * 32 * sizeof(float);
    unsigned short* K = (unsigned short*)w;
    size_t need = (size_t)(w - (char*)d_ws) + (size_t)NPIX * NPIX * sizeof(unsigned short);
    bool fast = (ws_size >= need);

    float* Qout = (float*)d_out;

    k_prep<<<(NPIX + 255) / 256, 256, 0, stream>>>(I, fx, fy, fr, fg, fb, S, nsp);
    if (fast) k_K<true ><<<NPIX / 16, 256, 0, stream>>>(fx, fy, fr, fg, fb, S, nbi, K);
    else      k_K<false><<<NPIX / 16, 256, 0, stream>>>(fx, fy, fr, fg, fb, S, nbi, nullptr);
    k_q0<<<(NPIX + 255) / 256, 256, 0, stream>>>(U, nbi, nsp, A, Qtb[0], Qtb[1]);

    for (int t = 0; t < N_ITER; ++t) {
        const unsigned short* Qtin = Qtb[t & 1];
        unsigned short* Qtout = Qtb[(t + 1) & 1];
        if (fast) {
            k_bi_fast<<<NITB * JCH, 256, 0, stream>>>(K, Qtin, A, nsp, U, SP, P);
            k_red<<<NPIX / 32, 64, 0, stream>>>(P, SP, nbi, nsp, Qout, A, Qtout);
        } else {
            k_sp<<<NSPB, 256, 0, stream>>>(A, nsp, U, SP);
            k_bi_slow<<<NPIX / 16, 256, 0, stream>>>(fx, fy, fr, fg, fb, nbi, Qtin, SP, nsp, Qout, A, Qtout);
        }
    }
}

// Round 7
// 520.703 us; speedup vs baseline: 1.9511x; 1.0649x over previous
//
#include <hip/hip_runtime.h>
#include <hip/hip_bf16.h>
#include <stddef.h>

#define HH 96
#define WW 96
#define NPIX 9216
#define LBL 21
#define LPAD 32
#define RAD 9            // int(3 * POS_STD)
#define N_ITER 10
#define POS_W_C 3.0f
#define BI_W_C 10.0f
#define INV_XY (1.0f/80.0f)
#define INV_RGB (1.0f/13.0f)

// bilateral GEMM blocking
#define JCH 16                       // j chunks (block dimension)
#define JC (NPIX / JCH)              // 576 columns per chunk
#define JTOT (NPIX / 32)             // 288 jt-tiles (swizzled K)
#define ROWB (JC * 2 + 16)           // 1168 B LDS row stride (292 words: m,m+8 -> 2-way, free)
#define CHROW (ROWB / 16)            // 73 16B-chunks per LDS row
#define TOTCH (32 * CHROW)           // 2336 chunks to stage
#define ITILE 128                    // rows per block (4 waves x 2 subtiles x 16)
#define NITB (NPIX / ITILE)          // 72 i-blocks
#define NSPB (LBL * 24)              // 504 conv bands (4 rows each)
#define KSPLIT 4                     // k_K j-split factor
#define PSTR 24                      // P inner stride (floats)

typedef __bf16 bf16x8 __attribute__((ext_vector_type(8)));
typedef float  f32x4  __attribute__((ext_vector_type(4)));

// exp(-0.5*(d/3)^2), d = -9..9  (matches reference _gauss1d(3.0))
__device__ const float GK[2 * RAD + 1] = {
    0.01110900f, 0.02856548f, 0.06572886f, 0.13533528f, 0.24935220f,
    0.41111229f, 0.60653066f, 0.80073740f, 0.94595947f, 1.00000000f,
    0.94595947f, 0.80073740f, 0.60653066f, 0.41111229f, 0.24935220f,
    0.13533528f, 0.06572886f, 0.02856548f, 0.01110900f
};

__device__ __forceinline__ unsigned short f2bf(float f) {
    unsigned u = __float_as_uint(f);
    unsigned r = (u + 0x7fffu + ((u >> 16) & 1u)) >> 16;
    return (unsigned short)r;
}
__device__ __forceinline__ float bf2f(unsigned short s) {
    return __uint_as_float(((unsigned)s) << 16);
}
__device__ __forceinline__ unsigned pk2bf(float a, float b) {
    __hip_bfloat162 h = __float22bfloat162_rn(make_float2(a, b));
    return *(unsigned*)&h;
}

// ---------------------------------------------------------------- k_prep
__global__ void k_prep(const float* __restrict__ I,
                       float* __restrict__ fx, float* __restrict__ fy,
                       float* __restrict__ fr, float* __restrict__ fg,
                       float* __restrict__ fb, float* __restrict__ S,
                       float* __restrict__ nsp) {
    int n = blockIdx.x * 256 + threadIdx.x;
    if (n >= NPIX) return;
    int y = n / WW, x = n % WW;
    float vx = (float)x * INV_XY;
    float vy = (float)y * INV_XY;
    float vr = I[n] * INV_RGB;
    float vg = I[NPIX + n] * INV_RGB;
    float vb = I[2 * NPIX + n] * INV_RGB;
    fx[n] = vx; fy[n] = vy; fr[n] = vr; fg[n] = vg; fb[n] = vb;
    S[n] = -0.5f * (vx*vx + vy*vy + vr*vr + vg*vg + vb*vb);
    float sy = 0.f, sx = 0.f;
    #pragma unroll
    for (int d = -RAD; d <= RAD; ++d) {
        float g = GK[d + RAD];
        if ((unsigned)(y + d) < HH) sy += g;
        if ((unsigned)(x + d) < WW) sx += g;
    }
    nsp[n] = rsqrtf(sy * sx);
}

// ---------------------------------------------------------------- k_K
// grid = (NPIX/16) * KSPLIT. Block (it, part): 16 i-rows, jtiles
// [part*72, part*72+72). Thread owns slot (tid&63) of jtile pass*4+(tid>>6):
// 8 consecutive j, one uint4 store -> 4KB contiguous per pass.
// Layout (matches k_bi A-frag): flat = ((it*JTOT + jtile)*64 + slot)*8 + e.
// Partial row sums -> RS[part][i]; k_q0 folds into nbi.
template <bool STORE>
__global__ void __launch_bounds__(256)
k_K(const float* __restrict__ fx, const float* __restrict__ fy,
    const float* __restrict__ fr, const float* __restrict__ fg,
    const float* __restrict__ fb, const float* __restrict__ S,
    float* __restrict__ RS, unsigned short* __restrict__ K) {
    int it = blockIdx.x >> 2;
    int part = blockIdx.x & 3;
    int tid = threadIdx.x;
    int m = tid & 15;
    int g = tid >> 4;        // ts*4 + khs
    int khs = g & 3;
    int ts = g >> 2;
    int i = it * 16 + m;
    float hx = fx[i], hy = fy[i], hr = fr[i], hg = fg[i], hb = fb[i];
    float ci = S[i];
    unsigned short* Kb = K + (size_t)it * JTOT * 512;
    float sum = 0.f;
    for (int pass = 0; pass < JTOT / (4 * KSPLIT); ++pass) {   // 18 passes
        int jtile = part * (JTOT / KSPLIT) + pass * 4 + ts;
        int j = jtile * 32 + khs * 8;
        float4 x0 = *(const float4*)(fx + j), x1 = *(const float4*)(fx + j + 4);
        float4 y0 = *(const float4*)(fy + j), y1 = *(const float4*)(fy + j + 4);
        float4 r0 = *(const float4*)(fr + j), r1 = *(const float4*)(fr + j + 4);
        float4 g0 = *(const float4*)(fg + j), g1 = *(const float4*)(fg + j + 4);
        float4 b0 = *(const float4*)(fb + j), b1 = *(const float4*)(fb + j + 4);
        float4 s0 = *(const float4*)(S + j),  s1 = *(const float4*)(S + j + 4);
        float k0 = __expf(ci + s0.x + hx*x0.x + hy*y0.x + hr*r0.x + hg*g0.x + hb*b0.x);
        float k1 = __expf(ci + s0.y + hx*x0.y + hy*y0.y + hr*r0.y + hg*g0.y + hb*b0.y);
        float k2 = __expf(ci + s0.z + hx*x0.z + hy*y0.z + hr*r0.z + hg*g0.z + hb*b0.z);
        float k3 = __expf(ci + s0.w + hx*x0.w + hy*y0.w + hr*r0.w + hg*g0.w + hb*b0.w);
        float k4 = __expf(ci + s1.x + hx*x1.x + hy*y1.x + hr*r1.x + hg*g1.x + hb*b1.x);
        float k5 = __expf(ci + s1.y + hx*x1.y + hy*y1.y + hr*r1.y + hg*g1.y + hb*b1.y);
        float k6 = __expf(ci + s1.z + hx*x1.z + hy*y1.z + hr*r1.z + hg*g1.z + hb*b1.z);
        float k7 = __expf(ci + s1.w + hx*x1.w + hy*y1.w + hr*r1.w + hg*g1.w + hb*b1.w);
        sum += ((k0 + k1) + (k2 + k3)) + ((k4 + k5) + (k6 + k7));
        if (STORE) {
            uint4 u;
            u.x = pk2bf(k0, k1);
            u.y = pk2bf(k2, k3);
            u.z = pk2bf(k4, k5);
            u.w = pk2bf(k6, k7);
            *(uint4*)(Kb + (size_t)jtile * 512 + (tid & 63) * 8) = u;
        }
    }
    __shared__ float red[16][17];
    red[g][m] = sum;
    __syncthreads();
    if (tid < 16) {
        float tot = 0.f;
        #pragma unroll
        for (int q = 0; q < 16; ++q) tot += red[q][tid];
        RS[part * NPIX + it * 16 + tid] = tot;
    }
}

// ---------------------------------------------------------------- k_q0
// folds RS partials into nbi, then softmax(-U) and emit A / Qt
__global__ void k_q0(const float* __restrict__ U, const float* __restrict__ RS,
                     const float* __restrict__ nsp,
                     float* __restrict__ nbi, float* __restrict__ A,
                     unsigned short* __restrict__ Qt0, unsigned short* __restrict__ Qt1) {
    int n = blockIdx.x * 256 + threadIdx.x;
    if (n >= NPIX) return;
    float nb = rsqrtf(RS[n] + RS[NPIX + n] + RS[2 * NPIX + n] + RS[3 * NPIX + n]);
    nbi[n] = nb;
    float v[LBL];
    float mx = -1e30f;
    #pragma unroll
    for (int l = 0; l < LBL; ++l) { v[l] = -U[l * NPIX + n]; mx = fmaxf(mx, v[l]); }
    float s = 0.f;
    #pragma unroll
    for (int l = 0; l < LBL; ++l) { v[l] = __expf(v[l] - mx); s += v[l]; }
    float inv = 1.f / s;
    float ns = nsp[n];
    #pragma unroll
    for (int l = 0; l < LBL; ++l) {
        float q = v[l] * inv;
        A[l * NPIX + n] = ns * q;
        Qt0[l * NPIX + n] = f2bf(nb * q);
    }
    #pragma unroll
    for (int l = LBL; l < LPAD; ++l) { Qt0[l * NPIX + n] = 0; Qt1[l * NPIX + n] = 0; }
}

// ---------------------------------------------------------------- k_sp
// slow-path only. SP = POS_W * nsp * Gx(Gy(A)) - U
__global__ void k_sp(const float* __restrict__ A, const float* __restrict__ nsp,
                     const float* __restrict__ U, float* __restrict__ SP) {
    __shared__ float ty[4 * WW];
    int l = blockIdx.x / 24;
    int y0 = (blockIdx.x % 24) * 4;
    int t = threadIdx.x;
    const float* Al = A + (size_t)l * NPIX;
    #pragma unroll
    for (int c = 0; c < 2; ++c) {
        int p = t + c * 256;
        if (p < 4 * WW) {
            int yy = p / WW, x = p % WW;
            int y = y0 + yy;
            float s = 0.f;
            #pragma unroll
            for (int d = -RAD; d <= RAD; ++d) {
                int yd = y + d;
                if ((unsigned)yd < HH) s += GK[d + RAD] * Al[yd * WW + x];
            }
            ty[p] = s;
        }
    }
    __syncthreads();
    #pragma unroll
    for (int c = 0; c < 2; ++c) {
        int p = t + c * 256;
        if (p < 4 * WW) {
            int yy = p / WW, x = p % WW;
            float s = 0.f;
            #pragma unroll
            for (int d = -RAD; d <= RAD; ++d) {
                int xd = x + d;
                if ((unsigned)xd < WW) s += GK[d + RAD] * ty[yy * WW + xd];
            }
            int pp = (y0 + yy) * WW + x;
            SP[(size_t)l * NPIX + pp] = POS_W_C * nsp[pp] * s - U[(size_t)l * NPIX + pp];
        }
    }
}

// ---------------------------------------------------------------- k_bi_fast
// grid = NITB*JCH = 1152. Blocks 0..503 first run one spatial-conv band
// (reusing Bsh LDS). Then: stage Qt[32][576] into LDS (37.4 KB -> 4 blk/CU);
// 4 waves x 2 i-subtiles (128 rows); K swizzled -> contiguous 1KB wave loads.
__global__ void __launch_bounds__(256)
k_bi_fast(const unsigned short* __restrict__ K, const unsigned short* __restrict__ Qt,
          const float* __restrict__ A, const float* __restrict__ nsp,
          const float* __restrict__ U, float* __restrict__ SP,
          float* __restrict__ P) {
    __shared__ __align__(16) unsigned short Bsh[32 * ROWB / 2];  // 37,376 B
    int tid = threadIdx.x;
    int bid = blockIdx.x;

    // ---- fused spatial conv band (blocks 0..503)
    if (bid < NSPB) {
        float* ty = (float*)Bsh;   // 4*96 floats
        int l = bid / 24;
        int y0b = (bid % 24) * 4;
        const float* Al = A + (size_t)l * NPIX;
        #pragma unroll
        for (int c = 0; c < 2; ++c) {
            int p = tid + c * 256;
            if (p < 4 * WW) {
                int yy = p / WW, x = p % WW;
                int y = y0b + yy;
                float s = 0.f;
                #pragma unroll
                for (int d = -RAD; d <= RAD; ++d) {
                    int yd = y + d;
                    if ((unsigned)yd < HH) s += GK[d + RAD] * Al[yd * WW + x];
                }
                ty[p] = s;
            }
        }
        __syncthreads();
        #pragma unroll
        for (int c = 0; c < 2; ++c) {
            int p = tid + c * 256;
            if (p < 4 * WW) {
                int yy = p / WW, x = p % WW;
                float s = 0.f;
                #pragma unroll
                for (int d = -RAD; d <= RAD; ++d) {
                    int xd = x + d;
                    if ((unsigned)xd < WW) s += GK[d + RAD] * ty[yy * WW + xd];
                }
                int pp = (y0b + yy) * WW + x;
                SP[(size_t)l * NPIX + pp] = POS_W_C * nsp[pp] * s - U[(size_t)l * NPIX + pp];
            }
        }
        __syncthreads();
    }

    int jc  = bid / NITB;          // 0..15
    int itb = bid % NITB;          // 0..71
    int base_j = jc * JC;
    int jtb = jc * (JC / 32);      // 18 jtiles per chunk

    // ---- stage Qt chunk
    for (int itn = 0; itn < (TOTCH + 255) / 256; ++itn) {
        int c = itn * 256 + tid;
        if (c < TOTCH) {
            int l = c / CHROW;
            int off = c - l * CHROW;
            int off16 = (off == CHROW - 1) ? 0 : off; // pad chunk: never read
            uint4 v = *(const uint4*)(Qt + (size_t)l * NPIX + base_j + off16 * 8);
            *((uint4*)Bsh + c) = v;
        }
    }
    __syncthreads();

    int lane = tid & 63;
    int wv = tid >> 6;
    int m  = lane & 15;
    int kh = lane >> 4;

    const bf16x8* pa0 = (const bf16x8*)K + ((size_t)(itb * 8 + wv)     * JTOT + jtb) * 64 + lane;
    const bf16x8* pa1 = (const bf16x8*)K + ((size_t)(itb * 8 + 4 + wv) * JTOT + jtb) * 64 + lane;
    const char* lb0 = (const char*)Bsh + m * ROWB + kh * 16;
    const char* lb1 = (const char*)Bsh + (m + 16) * ROWB + kh * 16;

    f32x4 acc00 = {0.f,0.f,0.f,0.f}, acc01 = {0.f,0.f,0.f,0.f};
    f32x4 acc10 = {0.f,0.f,0.f,0.f}, acc11 = {0.f,0.f,0.f,0.f};

    #pragma unroll 6
    for (int jt = 0; jt < JC / 32; ++jt) {     // 18 iters
        bf16x8 a0 = pa0[jt * 64];
        bf16x8 a1 = pa1[jt * 64];
        bf16x8 b0 = *(const bf16x8*)(lb0 + jt * 64);
        bf16x8 b1 = *(const bf16x8*)(lb1 + jt * 64);
        acc00 = __builtin_amdgcn_mfma_f32_16x16x32_bf16(a0, b0, acc00, 0, 0, 0);
        acc01 = __builtin_amdgcn_mfma_f32_16x16x32_bf16(a0, b1, acc01, 0, 0, 0);
        acc10 = __builtin_amdgcn_mfma_f32_16x16x32_bf16(a1, b0, acc10, 0, 0, 0);
        acc11 = __builtin_amdgcn_mfma_f32_16x16x32_bf16(a1, b1, acc11, 0, 0, 0);
    }

    float* Pp = P + (size_t)jc * NPIX * PSTR;
    int i0 = itb * 128 + wv * 16 + kh * 4;
    int i1 = i0 + 64;
    #pragma unroll
    for (int r = 0; r < 4; ++r) {
        Pp[(size_t)(i0 + r) * PSTR + m] = acc00[r];
        Pp[(size_t)(i1 + r) * PSTR + m] = acc10[r];
        if (m < 8) {
            Pp[(size_t)(i0 + r) * PSTR + 16 + m] = acc01[r];
            Pp[(size_t)(i1 + r) * PSTR + 16 + m] = acc11[r];
        }
    }
}

// ---------------------------------------------------------------- k_red
__global__ void __launch_bounds__(64)
k_red(const float* __restrict__ P, const float* __restrict__ SP,
      const float* __restrict__ nbi, const float* __restrict__ nsp,
      float* __restrict__ Qo, float* __restrict__ Ao,
      unsigned short* __restrict__ Qto) {
    int lane = threadIdx.x;
    int p = blockIdx.x * 32 + (lane & 31);
    int h = lane >> 5;
    float4 s[6] = {{0,0,0,0},{0,0,0,0},{0,0,0,0},{0,0,0,0},{0,0,0,0},{0,0,0,0}};
    #pragma unroll
    for (int jj = 0; jj < JCH / 2; ++jj) {
        int jcc = h * (JCH / 2) + jj;
        const float4* pp = (const float4*)(P + ((size_t)jcc * NPIX + p) * PSTR);
        #pragma unroll
        for (int q = 0; q < 6; ++q) s[q] += pp[q];
    }
    float bi[24];
    #pragma unroll
    for (int q = 0; q < 6; ++q) {
        bi[4*q+0] = s[q].x + __shfl_down(s[q].x, 32);
        bi[4*q+1] = s[q].y + __shfl_down(s[q].y, 32);
        bi[4*q+2] = s[q].z + __shfl_down(s[q].z, 32);
        bi[4*q+3] = s[q].w + __shfl_down(s[q].w, 32);
    }
    if (h) return;

    float nb = nbi[p];
    float ns = nsp[p];
    float v[LBL];
    float mx = -1e30f;
    #pragma unroll
    for (int l = 0; l < LBL; ++l) {
        v[l] = SP[l * NPIX + p] + BI_W_C * nb * bi[l];
        mx = fmaxf(mx, v[l]);
    }
    float ssum = 0.f;
    #pragma unroll
    for (int l = 0; l < LBL; ++l) { v[l] = __expf(v[l] - mx); ssum += v[l]; }
    float inv = 1.f / ssum;
    #pragma unroll
    for (int l = 0; l < LBL; ++l) {
        float q = v[l] * inv;
        Qo[l * NPIX + p] = q;
        Ao[l * NPIX + p] = ns * q;
        Qto[l * NPIX + p] = f2bf(nb * q);
    }
}

// ---------------------------------------------------------------- k_bi_slow
__global__ void k_bi_slow(const float* __restrict__ fx, const float* __restrict__ fy,
                          const float* __restrict__ fr, const float* __restrict__ fg,
                          const float* __restrict__ fb,
                          const float* __restrict__ nbi, const unsigned short* __restrict__ Qt,
                          const float* __restrict__ SP, const float* __restrict__ nsp,
                          float* __restrict__ Qo, float* __restrict__ Ao,
                          unsigned short* __restrict__ Qto) {
    int t = threadIdx.x;
    int px = t & 15, st = t >> 4;
    int i = blockIdx.x * 16 + px;
    float xi = fx[i], yi = fy[i], ri = fr[i], gi = fg[i], bi = fb[i];
    float acc[LBL];
    #pragma unroll
    for (int l = 0; l < LBL; ++l) acc[l] = 0.f;
    int j0 = st * (NPIX / 16);
    for (int j = j0; j < j0 + NPIX / 16; ++j) {
        float dx = xi - fx[j], dy = yi - fy[j];
        float dr = ri - fr[j], dg = gi - fg[j], db = bi - fb[j];
        float D = dx*dx + dy*dy + dr*dr + dg*dg + db*db;
        float w = __expf(-0.5f * D);
        #pragma unroll
        for (int l = 0; l < LBL; ++l) acc[l] += w * bf2f(Qt[l * NPIX + j]);
    }
    __shared__ float red[16][LBL];
    if (st == 0) {
        #pragma unroll
        for (int l = 0; l < LBL; ++l) red[px][l] = acc[l];
    }
    __syncthreads();
    for (int s = 1; s < 16; ++s) {
        if (st == s) {
            #pragma unroll
            for (int l = 0; l < LBL; ++l) red[px][l] += acc[l];
        }
        __syncthreads();
    }
    if (t < 16) {
        int i2 = blockIdx.x * 16 + t;
        float nb = nbi[i2];
        float ns = nsp[i2];
        float v[LBL];
        float mx = -1e30f;
        #pragma unroll
        for (int l = 0; l < LBL; ++l) {
            v[l] = SP[l * NPIX + i2] + BI_W_C * nb * red[t][l];
            mx = fmaxf(mx, v[l]);
        }
        float s = 0.f;
        #pragma unroll
        for (int l = 0; l < LBL; ++l) { v[l] = __expf(v[l] - mx); s += v[l]; }
        float inv = 1.f / s;
        #pragma unroll
        for (int l = 0; l < LBL; ++l) {
            float q = v[l] * inv;
            Qo[l * NPIX + i2] = q;
            Ao[l * NPIX + i2] = ns * q;
            Qto[l * NPIX + i2] = f2bf(nb * q);
        }
    }
}

// ---------------------------------------------------------------- launch
extern "C" void kernel_launch(void* const* d_in, const int* in_sizes, int n_in,
                              void* d_out, int out_size, void* d_ws, size_t ws_size,
                              hipStream_t stream) {
    const float* U = (const float*)d_in[0];
    const float* I = (const float*)d_in[1];

    char* w = (char*)d_ws;
    float* fx  = (float*)w;                 w += NPIX * sizeof(float);
    float* fy  = (float*)w;                 w += NPIX * sizeof(float);
    float* fr  = (float*)w;                 w += NPIX * sizeof(float);
    float* fg  = (float*)w;                 w += NPIX * sizeof(float);
    float* fb  = (float*)w;                 w += NPIX * sizeof(float);
    float* S   = (float*)w;                 w += NPIX * sizeof(float);
    float* nsp = (float*)w;                 w += NPIX * sizeof(float);
    float* nbi = (float*)w;                 w += NPIX * sizeof(float);
    float* RS  = (float*)w;                 w += (size_t)KSPLIT * NPIX * sizeof(float);
    float* A   = (float*)w;                 w += (size_t)LBL * NPIX * sizeof(float);
    float* SP  = (float*)w;                 w += (size_t)LBL * NPIX * sizeof(float);
    unsigned short* Qtb[2];
    Qtb[0] = (unsigned short*)w;            w += (size_t)LPAD * NPIX * sizeof(unsigned short);
    Qtb[1] = (unsigned short*)w;            w += (size_t)LPAD * NPIX * sizeof(unsigned short);
    float* P = (float*)w;                   w += (size_t)JCH * NPIX * PSTR * sizeof(float);
    unsigned short* K = (unsigned short*)w;
    size_t need = (size_t)(w - (char*)d_ws) + (size_t)NPIX * NPIX * sizeof(unsigned short);
    bool fast = (ws_size >= need);

    float* Qout = (float*)d_out;

    k_prep<<<(NPIX + 255) / 256, 256, 0, stream>>>(I, fx, fy, fr, fg, fb, S, nsp);
    if (fast) k_K<true ><<<(NPIX / 16) * KSPLIT, 256, 0, stream>>>(fx, fy, fr, fg, fb, S, RS, K);
    else      k_K<false><<<(NPIX / 16) * KSPLIT, 256, 0, stream>>>(fx, fy, fr, fg, fb, S, RS, nullptr);
    k_q0<<<(NPIX + 255) / 256, 256, 0, stream>>>(U, RS, nsp, nbi, A, Qtb[0], Qtb[1]);

    for (int t = 0; t < N_ITER; ++t) {
        const unsigned short* Qtin = Qtb[t & 1];
        unsigned short* Qtout = Qtb[(t + 1) & 1];
        if (fast) {
            k_bi_fast<<<NITB * JCH, 256, 0, stream>>>(K, Qtin, A, nsp, U, SP, P);
            k_red<<<NPIX / 32, 64, 0, stream>>>(P, SP, nbi, nsp, Qout, A, Qtout);
        } else {
            k_sp<<<NSPB, 256, 0, stream>>>(A, nsp, U, SP);
            k_bi_slow<<<NPIX / 16, 256, 0, stream>>>(fx, fy, fr, fg, fb, nbi, Qtin, SP, nsp, Qout, A, Qtout);
        }
    }
}

// Round 8
// 509.419 us; speedup vs baseline: 1.9943x; 1.0222x over previous
//
#include <hip/hip_runtime.h>
#include <hip/hip_bf16.h>
#include <stddef.h>

#define HH 96
#define WW 96
#define NPIX 9216
#define LBL 21
#define LPAD 32
#define RAD 9            // int(3 * POS_STD)
#define N_ITER 10
#define POS_W_C 3.0f
#define BI_W_C 10.0f
#define INV_XY (1.0f/80.0f)
#define INV_RGB (1.0f/13.0f)

// bilateral GEMM blocking
#define JCH 16                       // j chunks (block dimension)
#define JC (NPIX / JCH)              // 576 columns per chunk
#define JTOT (NPIX / 32)             // 288 jt-tiles (swizzled layouts)
#define ITILE 64                     // rows per block (4 waves x 16)
#define NITB (NPIX / ITILE)          // 144 i-blocks
#define NSPB (LBL * 24)              // 504 conv bands (4 rows each)
#define KSPLIT 8                     // k_K j-split factor
#define PSTR 24                      // P inner stride (floats)
#define QHALF (JTOT * 64 * 8)        // 147456 ushorts per Qt half-buffer

typedef __bf16 bf16x8 __attribute__((ext_vector_type(8)));
typedef float  f32x4  __attribute__((ext_vector_type(4)));

// exp(-0.5*(d/3)^2), d = -9..9  (matches reference _gauss1d(3.0))
__device__ const float GK[2 * RAD + 1] = {
    0.01110900f, 0.02856548f, 0.06572886f, 0.13533528f, 0.24935220f,
    0.41111229f, 0.60653066f, 0.80073740f, 0.94595947f, 1.00000000f,
    0.94595947f, 0.80073740f, 0.60653066f, 0.41111229f, 0.24935220f,
    0.13533528f, 0.06572886f, 0.02856548f, 0.01110900f
};

__device__ __forceinline__ unsigned short f2bf(float f) {
    unsigned u = __float_as_uint(f);
    unsigned r = (u + 0x7fffu + ((u >> 16) & 1u)) >> 16;
    return (unsigned short)r;
}
__device__ __forceinline__ float bf2f(unsigned short s) {
    return __uint_as_float(((unsigned)s) << 16);
}
__device__ __forceinline__ unsigned pk2bf(float a, float b) {
    __hip_bfloat162 h = __float22bfloat162_rn(make_float2(a, b));
    return *(unsigned*)&h;
}
// swizzled Qt element index for (pixel p, label l)
__device__ __forceinline__ size_t qtidx(int p, int l) {
    size_t half = (l >> 4) ? (size_t)QHALF : 0;
    return half + ((((p >> 5) * 64 + ((p >> 3) & 3) * 16 + (l & 15)) << 3) + (p & 7));
}

// ---------------------------------------------------------------- k_prep
__global__ void k_prep(const float* __restrict__ I,
                       float* __restrict__ fx, float* __restrict__ fy,
                       float* __restrict__ fr, float* __restrict__ fg,
                       float* __restrict__ fb, float* __restrict__ S,
                       float* __restrict__ nsp) {
    int n = blockIdx.x * 256 + threadIdx.x;
    if (n >= NPIX) return;
    int y = n / WW, x = n % WW;
    float vx = (float)x * INV_XY;
    float vy = (float)y * INV_XY;
    float vr = I[n] * INV_RGB;
    float vg = I[NPIX + n] * INV_RGB;
    float vb = I[2 * NPIX + n] * INV_RGB;
    fx[n] = vx; fy[n] = vy; fr[n] = vr; fg[n] = vg; fb[n] = vb;
    S[n] = -0.5f * (vx*vx + vy*vy + vr*vr + vg*vg + vb*vb);
    float sy = 0.f, sx = 0.f;
    #pragma unroll
    for (int d = -RAD; d <= RAD; ++d) {
        float g = GK[d + RAD];
        if ((unsigned)(y + d) < HH) sy += g;
        if ((unsigned)(x + d) < WW) sx += g;
    }
    nsp[n] = rsqrtf(sy * sx);
}

// ---------------------------------------------------------------- k_K
// grid = (NPIX/16) * KSPLIT. Block (it, part): 16 i-rows, 36 jtiles.
// Thread owns slot (tid&63) of jtile pass*4+(tid>>6): 8 consecutive j,
// one uint4 store -> 4KB contiguous per pass.
template <bool STORE>
__global__ void __launch_bounds__(256)
k_K(const float* __restrict__ fx, const float* __restrict__ fy,
    const float* __restrict__ fr, const float* __restrict__ fg,
    const float* __restrict__ fb, const float* __restrict__ S,
    float* __restrict__ RS, unsigned short* __restrict__ K) {
    int it = blockIdx.x >> 3;
    int part = blockIdx.x & 7;
    int tid = threadIdx.x;
    int m = tid & 15;
    int g = tid >> 4;        // ts*4 + khs
    int khs = g & 3;
    int ts = g >> 2;
    int i = it * 16 + m;
    float hx = fx[i], hy = fy[i], hr = fr[i], hg = fg[i], hb = fb[i];
    float ci = S[i];
    unsigned short* Kb = K + (size_t)it * JTOT * 512;
    float sum = 0.f;
    for (int pass = 0; pass < JTOT / (4 * KSPLIT); ++pass) {   // 9 passes
        int jtile = part * (JTOT / KSPLIT) + pass * 4 + ts;
        int j = jtile * 32 + khs * 8;
        float4 x0 = *(const float4*)(fx + j), x1 = *(const float4*)(fx + j + 4);
        float4 y0 = *(const float4*)(fy + j), y1 = *(const float4*)(fy + j + 4);
        float4 r0 = *(const float4*)(fr + j), r1 = *(const float4*)(fr + j + 4);
        float4 g0 = *(const float4*)(fg + j), g1 = *(const float4*)(fg + j + 4);
        float4 b0 = *(const float4*)(fb + j), b1 = *(const float4*)(fb + j + 4);
        float4 s0 = *(const float4*)(S + j),  s1 = *(const float4*)(S + j + 4);
        float k0 = __expf(ci + s0.x + hx*x0.x + hy*y0.x + hr*r0.x + hg*g0.x + hb*b0.x);
        float k1 = __expf(ci + s0.y + hx*x0.y + hy*y0.y + hr*r0.y + hg*g0.y + hb*b0.y);
        float k2 = __expf(ci + s0.z + hx*x0.z + hy*y0.z + hr*r0.z + hg*g0.z + hb*b0.z);
        float k3 = __expf(ci + s0.w + hx*x0.w + hy*y0.w + hr*r0.w + hg*g0.w + hb*b0.w);
        float k4 = __expf(ci + s1.x + hx*x1.x + hy*y1.x + hr*r1.x + hg*g1.x + hb*b1.x);
        float k5 = __expf(ci + s1.y + hx*x1.y + hy*y1.y + hr*r1.y + hg*g1.y + hb*b1.y);
        float k6 = __expf(ci + s1.z + hx*x1.z + hy*y1.z + hr*r1.z + hg*g1.z + hb*b1.z);
        float k7 = __expf(ci + s1.w + hx*x1.w + hy*y1.w + hr*r1.w + hg*g1.w + hb*b1.w);
        sum += ((k0 + k1) + (k2 + k3)) + ((k4 + k5) + (k6 + k7));
        if (STORE) {
            uint4 u;
            u.x = pk2bf(k0, k1);
            u.y = pk2bf(k2, k3);
            u.z = pk2bf(k4, k5);
            u.w = pk2bf(k6, k7);
            *(uint4*)(Kb + (size_t)jtile * 512 + (tid & 63) * 8) = u;
        }
    }
    __shared__ float red[16][17];
    red[g][m] = sum;
    __syncthreads();
    if (tid < 16) {
        float tot = 0.f;
        #pragma unroll
        for (int q = 0; q < 16; ++q) tot += red[q][tid];
        RS[part * NPIX + it * 16 + tid] = tot;
    }
}

// ---------------------------------------------------------------- k_q0
// folds RS partials into nbi, softmax(-U), emits A + swizzled Qt (both buffers' pads)
__global__ void k_q0(const float* __restrict__ U, const float* __restrict__ RS,
                     const float* __restrict__ nsp,
                     float* __restrict__ nbi, float* __restrict__ A,
                     unsigned short* __restrict__ Qt0, unsigned short* __restrict__ Qt1) {
    int n = blockIdx.x * 256 + threadIdx.x;
    if (n >= NPIX) return;
    float rs = 0.f;
    #pragma unroll
    for (int q = 0; q < KSPLIT; ++q) rs += RS[q * NPIX + n];
    float nb = rsqrtf(rs);
    nbi[n] = nb;
    float v[LBL];
    float mx = -1e30f;
    #pragma unroll
    for (int l = 0; l < LBL; ++l) { v[l] = -U[l * NPIX + n]; mx = fmaxf(mx, v[l]); }
    float s = 0.f;
    #pragma unroll
    for (int l = 0; l < LBL; ++l) { v[l] = __expf(v[l] - mx); s += v[l]; }
    float inv = 1.f / s;
    float ns = nsp[n];
    #pragma unroll
    for (int l = 0; l < LBL; ++l) {
        float q = v[l] * inv;
        A[l * NPIX + n] = ns * q;
        Qt0[qtidx(n, l)] = f2bf(nb * q);
    }
    #pragma unroll
    for (int l = LBL; l < LPAD; ++l) {
        Qt0[qtidx(n, l)] = 0;
        Qt1[qtidx(n, l)] = 0;
    }
}

// ---------------------------------------------------------------- k_sp (slow path)
__global__ void k_sp(const float* __restrict__ A, const float* __restrict__ nsp,
                     const float* __restrict__ U, float* __restrict__ SP) {
    __shared__ float ty[4 * WW];
    int l = blockIdx.x / 24;
    int y0 = (blockIdx.x % 24) * 4;
    int t = threadIdx.x;
    const float* Al = A + (size_t)l * NPIX;
    #pragma unroll
    for (int c = 0; c < 2; ++c) {
        int p = t + c * 256;
        if (p < 4 * WW) {
            int yy = p / WW, x = p % WW;
            int y = y0 + yy;
            float s = 0.f;
            #pragma unroll
            for (int d = -RAD; d <= RAD; ++d) {
                int yd = y + d;
                if ((unsigned)yd < HH) s += GK[d + RAD] * Al[yd * WW + x];
            }
            ty[p] = s;
        }
    }
    __syncthreads();
    #pragma unroll
    for (int c = 0; c < 2; ++c) {
        int p = t + c * 256;
        if (p < 4 * WW) {
            int yy = p / WW, x = p % WW;
            float s = 0.f;
            #pragma unroll
            for (int d = -RAD; d <= RAD; ++d) {
                int xd = x + d;
                if ((unsigned)xd < WW) s += GK[d + RAD] * ty[yy * WW + xd];
            }
            int pp = (y0 + yy) * WW + x;
            SP[(size_t)l * NPIX + pp] = POS_W_C * nsp[pp] * s - U[(size_t)l * NPIX + pp];
        }
    }
}

// ---------------------------------------------------------------- k_bi_fast
// grid = NITB*JCH = 2304, LDS-free GEMM. Blocks 0..503 first run one
// spatial-conv band. Each wave: 16 i-rows, 18 jt tiles; A (K) and B (Qt)
// both in MFMA-swizzled layout -> contiguous 1KB wave loads; B is L2-hot.
__global__ void __launch_bounds__(256, 8)
k_bi_fast(const unsigned short* __restrict__ K, const unsigned short* __restrict__ Qt,
          const float* __restrict__ A, const float* __restrict__ nsp,
          const float* __restrict__ U, float* __restrict__ SP,
          float* __restrict__ P) {
    int tid = threadIdx.x;
    int bid = blockIdx.x;

    // ---- fused spatial conv band (blocks 0..503)
    __shared__ float ty[4 * WW];
    if (bid < NSPB) {
        int l = bid / 24;
        int y0b = (bid % 24) * 4;
        const float* Al = A + (size_t)l * NPIX;
        #pragma unroll
        for (int c = 0; c < 2; ++c) {
            int p = tid + c * 256;
            if (p < 4 * WW) {
                int yy = p / WW, x = p % WW;
                int y = y0b + yy;
                float s = 0.f;
                #pragma unroll
                for (int d = -RAD; d <= RAD; ++d) {
                    int yd = y + d;
                    if ((unsigned)yd < HH) s += GK[d + RAD] * Al[yd * WW + x];
                }
                ty[p] = s;
            }
        }
        __syncthreads();
        #pragma unroll
        for (int c = 0; c < 2; ++c) {
            int p = tid + c * 256;
            if (p < 4 * WW) {
                int yy = p / WW, x = p % WW;
                float s = 0.f;
                #pragma unroll
                for (int d = -RAD; d <= RAD; ++d) {
                    int xd = x + d;
                    if ((unsigned)xd < WW) s += GK[d + RAD] * ty[yy * WW + xd];
                }
                int pp = (y0b + yy) * WW + x;
                SP[(size_t)l * NPIX + pp] = POS_W_C * nsp[pp] * s - U[(size_t)l * NPIX + pp];
            }
        }
    }

    int jc  = bid / NITB;          // 0..15
    int itb = bid % NITB;          // 0..143
    int jtb = jc * (JC / 32);      // 18 jtiles per chunk

    int lane = tid & 63;
    int wv = tid >> 6;
    int m  = lane & 15;
    int kh = lane >> 4;
    int it = itb * 4 + wv;         // 16-row i-tile

    const bf16x8* pa  = (const bf16x8*)K  + ((size_t)it * JTOT + jtb) * 64 + lane;
    const bf16x8* pb0 = (const bf16x8*)Qt + (size_t)jtb * 64 + lane;
    const bf16x8* pb1 = (const bf16x8*)Qt + (size_t)(QHALF / 8) + (size_t)jtb * 64 + lane;

    f32x4 acc0 = {0.f,0.f,0.f,0.f}, acc1 = {0.f,0.f,0.f,0.f};

    #pragma unroll 6
    for (int jt = 0; jt < JC / 32; ++jt) {     // 18 iters
        bf16x8 a  = pa[jt * 64];
        bf16x8 b0 = pb0[jt * 64];
        bf16x8 b1 = pb1[jt * 64];
        acc0 = __builtin_amdgcn_mfma_f32_16x16x32_bf16(a, b0, acc0, 0, 0, 0);
        acc1 = __builtin_amdgcn_mfma_f32_16x16x32_bf16(a, b1, acc1, 0, 0, 0);
    }

    // partials; C/D layout col(label)=m, row=kh*4+r
    float* Pp = P + (size_t)jc * NPIX * PSTR;
    int i0 = it * 16 + kh * 4;
    #pragma unroll
    for (int r = 0; r < 4; ++r) {
        Pp[(size_t)(i0 + r) * PSTR + m] = acc0[r];
        if (m < 8) Pp[(size_t)(i0 + r) * PSTR + 16 + m] = acc1[r];
    }
}

// ---------------------------------------------------------------- k_red
// 288 blocks x 256: 8 groups each sum 2 j-chunks; LDS reduce (stride-25 pad);
// wave-0 lanes do fused softmax epilogue + swizzled Qt writes.
__global__ void __launch_bounds__(256)
k_red(const float* __restrict__ P, const float* __restrict__ SP,
      const float* __restrict__ nbi, const float* __restrict__ nsp,
      float* __restrict__ Qo, float* __restrict__ Ao,
      unsigned short* __restrict__ Qto) {
    __shared__ float red[8][32][25];
    int tid = threadIdx.x;
    int p32 = tid & 31;
    int g = tid >> 5;
    int p = blockIdx.x * 32 + p32;

    float4 s[6] = {{0,0,0,0},{0,0,0,0},{0,0,0,0},{0,0,0,0},{0,0,0,0},{0,0,0,0}};
    #pragma unroll
    for (int jj = 0; jj < 2; ++jj) {
        int jcc = g * 2 + jj;
        const float4* pp = (const float4*)(P + ((size_t)jcc * NPIX + p) * PSTR);
        #pragma unroll
        for (int q = 0; q < 6; ++q) s[q] += pp[q];
    }
    #pragma unroll
    for (int q = 0; q < 6; ++q) {
        red[g][p32][4*q+0] = s[q].x;
        red[g][p32][4*q+1] = s[q].y;
        red[g][p32][4*q+2] = s[q].z;
        red[g][p32][4*q+3] = s[q].w;
    }
    __syncthreads();
    if (tid >= 32) return;

    float nb = nbi[p];
    float ns = nsp[p];
    float v[LBL];
    float mx = -1e30f;
    #pragma unroll
    for (int l = 0; l < LBL; ++l) {
        float bi = 0.f;
        #pragma unroll
        for (int q = 0; q < 8; ++q) bi += red[q][p32][l];
        v[l] = SP[l * NPIX + p] + BI_W_C * nb * bi;
        mx = fmaxf(mx, v[l]);
    }
    float ssum = 0.f;
    #pragma unroll
    for (int l = 0; l < LBL; ++l) { v[l] = __expf(v[l] - mx); ssum += v[l]; }
    float inv = 1.f / ssum;
    #pragma unroll
    for (int l = 0; l < LBL; ++l) {
        float q = v[l] * inv;
        Qo[l * NPIX + p] = q;
        Ao[l * NPIX + p] = ns * q;
        Qto[qtidx(p, l)] = f2bf(nb * q);
    }
}

// ---------------------------------------------------------------- k_bi_slow
__global__ void k_bi_slow(const float* __restrict__ fx, const float* __restrict__ fy,
                          const float* __restrict__ fr, const float* __restrict__ fg,
                          const float* __restrict__ fb,
                          const float* __restrict__ nbi, const unsigned short* __restrict__ Qt,
                          const float* __restrict__ SP, const float* __restrict__ nsp,
                          float* __restrict__ Qo, float* __restrict__ Ao,
                          unsigned short* __restrict__ Qto) {
    int t = threadIdx.x;
    int px = t & 15, st = t >> 4;
    int i = blockIdx.x * 16 + px;
    float xi = fx[i], yi = fy[i], ri = fr[i], gi = fg[i], bi = fb[i];
    float acc[LBL];
    #pragma unroll
    for (int l = 0; l < LBL; ++l) acc[l] = 0.f;
    int j0 = st * (NPIX / 16);
    for (int j = j0; j < j0 + NPIX / 16; ++j) {
        float dx = xi - fx[j], dy = yi - fy[j];
        float dr = ri - fr[j], dg = gi - fg[j], db = bi - fb[j];
        float D = dx*dx + dy*dy + dr*dr + dg*dg + db*db;
        float w = __expf(-0.5f * D);
        #pragma unroll
        for (int l = 0; l < LBL; ++l) acc[l] += w * bf2f(Qt[qtidx(j, l)]);
    }
    __shared__ float red[16][LBL];
    if (st == 0) {
        #pragma unroll
        for (int l = 0; l < LBL; ++l) red[px][l] = acc[l];
    }
    __syncthreads();
    for (int s = 1; s < 16; ++s) {
        if (st == s) {
            #pragma unroll
            for (int l = 0; l < LBL; ++l) red[px][l] += acc[l];
        }
        __syncthreads();
    }
    if (t < 16) {
        int i2 = blockIdx.x * 16 + t;
        float nb = nbi[i2];
        float ns = nsp[i2];
        float v[LBL];
        float mx = -1e30f;
        #pragma unroll
        for (int l = 0; l < LBL; ++l) {
            v[l] = SP[l * NPIX + i2] + BI_W_C * nb * red[t][l];
            mx = fmaxf(mx, v[l]);
        }
        float s = 0.f;
        #pragma unroll
        for (int l = 0; l < LBL; ++l) { v[l] = __expf(v[l] - mx); s += v[l]; }
        float inv = 1.f / s;
        #pragma unroll
        for (int l = 0; l < LBL; ++l) {
            float q = v[l] * inv;
            Qo[l * NPIX + i2] = q;
            Ao[l * NPIX + i2] = ns * q;
            Qto[qtidx(i2, l)] = f2bf(nb * q);
        }
    }
}

// ---------------------------------------------------------------- launch
extern "C" void kernel_launch(void* const* d_in, const int* in_sizes, int n_in,
                              void* d_out, int out_size, void* d_ws, size_t ws_size,
                              hipStream_t stream) {
    const float* U = (const float*)d_in[0];
    const float* I = (const float*)d_in[1];

    char* w = (char*)d_ws;
    float* fx  = (float*)w;                 w += NPIX * sizeof(float);
    float* fy  = (float*)w;                 w += NPIX * sizeof(float);
    float* fr  = (float*)w;                 w += NPIX * sizeof(float);
    float* fg  = (float*)w;                 w += NPIX * sizeof(float);
    float* fb  = (float*)w;                 w += NPIX * sizeof(float);
    float* S   = (float*)w;                 w += NPIX * sizeof(float);
    float* nsp = (float*)w;                 w += NPIX * sizeof(float);
    float* nbi = (float*)w;                 w += NPIX * sizeof(float);
    float* RS  = (float*)w;                 w += (size_t)KSPLIT * NPIX * sizeof(float);
    float* A   = (float*)w;                 w += (size_t)LBL * NPIX * sizeof(float);
    float* SP  = (float*)w;                 w += (size_t)LBL * NPIX * sizeof(float);
    unsigned short* Qtb[2];
    Qtb[0] = (unsigned short*)w;            w += (size_t)2 * QHALF * sizeof(unsigned short);
    Qtb[1] = (unsigned short*)w;            w += (size_t)2 * QHALF * sizeof(unsigned short);
    float* P = (float*)w;                   w += (size_t)JCH * NPIX * PSTR * sizeof(float);
    unsigned short* K = (unsigned short*)w;
    size_t need = (size_t)(w - (char*)d_ws) + (size_t)NPIX * NPIX * sizeof(unsigned short);
    bool fast = (ws_size >= need);

    float* Qout = (float*)d_out;

    k_prep<<<(NPIX + 255) / 256, 256, 0, stream>>>(I, fx, fy, fr, fg, fb, S, nsp);
    if (fast) k_K<true ><<<(NPIX / 16) * KSPLIT, 256, 0, stream>>>(fx, fy, fr, fg, fb, S, RS, K);
    else      k_K<false><<<(NPIX / 16) * KSPLIT, 256, 0, stream>>>(fx, fy, fr, fg, fb, S, RS, nullptr);
    k_q0<<<(NPIX + 255) / 256, 256, 0, stream>>>(U, RS, nsp, nbi, A, Qtb[0], Qtb[1]);

    for (int t = 0; t < N_ITER; ++t) {
        const unsigned short* Qtin = Qtb[t & 1];
        unsigned short* Qtout = Qtb[(t + 1) & 1];
        if (fast) {
            k_bi_fast<<<NITB * JCH, 256, 0, stream>>>(K, Qtin, A, nsp, U, SP, P);
            k_red<<<NPIX / 32, 256, 0, stream>>>(P, SP, nbi, nsp, Qout, A, Qtout);
        } else {
            k_sp<<<NSPB, 256, 0, stream>>>(A, nsp, U, SP);
            k_bi_slow<<<NPIX / 16, 256, 0, stream>>>(fx, fy, fr, fg, fb, nbi, Qtin, SP, nsp, Qout, A, Qtout);
        }
    }
}